// Round 1
// 1104.743 us; speedup vs baseline: 1.1718x; 1.1718x over previous
//
#include <hip/hip_runtime.h>
#include <cstdint>
#include <cstddef>

#define NN 100000
#define BN_EPS 1e-5f

// bucketed CSR build: 128 nodes per bucket
#define NB_SHIFT 7
#define NBUCK ((NN >> NB_SHIFT) + 1)   // 782
#define T1_EPT 16
#define T1_TILE (256*T1_EPT)           // 4096 edges per pass-1 block

typedef __attribute__((ext_vector_type(8))) short short8;
typedef __attribute__((ext_vector_type(4))) float f32x4;

static __device__ __forceinline__ float bflo(unsigned u){ return __uint_as_float(u<<16); }
static __device__ __forceinline__ float bfhi(unsigned u){ return __uint_as_float(u & 0xFFFF0000u); }
static __device__ __forceinline__ unsigned short f2bf(float f){
  unsigned u = __float_as_uint(f);
  u += 0x7FFFu + ((u>>16)&1u);   // round-to-nearest-even
  return (unsigned short)(u>>16);
}
static __device__ __forceinline__ unsigned pk2(float a, float b){
  return (unsigned)f2bf(a) | ((unsigned)f2bf(b) << 16);
}

// ---------------- graph prep ----------------

__global__ void k_hist(const int* __restrict__ dst, int* __restrict__ cnt, int E){
  int e = blockIdx.x*blockDim.x + threadIdx.x;
  if(e<E) atomicAdd(&cnt[dst[e]], 1);
}

// norm over N+1: norm[NN] = 0 (zero row / pad-edge killer)
__global__ void k_norm(const int* __restrict__ cnt, float* __restrict__ norm, int n){
  int i = blockIdx.x*blockDim.x + threadIdx.x;
  if(i<=n) norm[i] = (i==n) ? 0.f : rsqrtf(fmaxf((float)cnt[i], 1.0f));
}

// exclusive scan over counts padded to multiple of 8
__global__ __launch_bounds__(1024) void k_scan(const int* __restrict__ cnt, int* __restrict__ rp, int n){
  __shared__ int sm[1024];
  int t = threadIdx.x;
  int chunk = (n + 1023)/1024;
  int lo = t*chunk, hi = min(lo+chunk, n);
  int s=0;
  for(int i=lo;i<hi;i++) s += (cnt[i]+7)&~7;
  sm[t]=s; __syncthreads();
  for(int off=1; off<1024; off<<=1){
    int v = (t>=off)? sm[t-off] : 0;
    __syncthreads();
    sm[t]+=v;
    __syncthreads();
  }
  int run = sm[t]-s;
  for(int i=lo;i<hi;i++){ rp[i]=run; run+=(cnt[i]+7)&~7; }
  if(t==1023) rp[n]=sm[1023];
}

// bucket fill pointers: one counter per 64B line (stride 16) to avoid
// same-line atomic serialization across the 50K pass-1 block appends.
__global__ void k_binit(const int* __restrict__ rp, int* __restrict__ bfill){
  int b = blockIdx.x*blockDim.x + threadIdx.x;
  if(b<NBUCK) bfill[b*16] = rp[min(b<<NB_SHIFT, NN)];
}

// pass 1: partition edges into NBUCK per-dst-range buckets of (src,dst) pairs.
// LDS histogram -> per-edge rank (LDS atomic return) -> one global atomic per
// (block,bucket) -> contiguous runs of pair writes into bucket regions.
// Bucket region base = rp[b<<7]; padded CSR layout guarantees capacity.
__global__ __launch_bounds__(256) void k_bucket1(const int* __restrict__ src,
    const int* __restrict__ dst, int* __restrict__ bfill,
    int2* __restrict__ epairs, int E){
  __shared__ int hist[NBUCK];
  int tid = threadIdx.x;
  for(int j=tid; j<NBUCK; j+=256) hist[j]=0;
  __syncthreads();
  int base = blockIdx.x*T1_TILE;
  int s[T1_EPT], d[T1_EPT], r[T1_EPT];
  #pragma unroll
  for(int i=0;i<T1_EPT;i++){
    int e = base + i*256 + tid;
    if(e<E){
      s[i]=src[e]; d[i]=dst[e];
      r[i]=atomicAdd(&hist[d[i]>>NB_SHIFT], 1);
    }
  }
  __syncthreads();
  for(int j=tid; j<NBUCK; j+=256){
    int h = hist[j];
    if(h>0) hist[j] = atomicAdd(&bfill[j*16], h);   // replace count with global base
  }
  __syncthreads();
  #pragma unroll
  for(int i=0;i<T1_EPT;i++){
    int e = base + i*256 + tid;
    if(e<E){
      int pos = hist[d[i]>>NB_SHIFT] + r[i];
      epairs[pos] = make_int2(s[i], d[i]);
    }
  }
}

// pass 2: one block per bucket. Fine scatter confined to a ~16KB esrc region
// owned by one XCD's L2 (lines fill completely before writeback). Per-node
// placement via LDS atomics (no global returning atomics). Also writes the
// pad slots (replaces k_pad) with NN (zero row).
__global__ __launch_bounds__(256) void k_bucket2(const int2* __restrict__ epairs,
    const int* __restrict__ bfill, const int* __restrict__ rp,
    int* __restrict__ esrc){
  __shared__ int fillLoc[1<<NB_SHIFT];
  int b = blockIdx.x, tid = threadIdx.x;
  int n0 = b << NB_SHIFT;
  int nmax = min(1<<NB_SHIFT, NN - n0);
  for(int i=tid; i<nmax; i+=256) fillLoc[i] = rp[n0+i];
  __syncthreads();
  int p0 = rp[n0];
  int cntb = bfill[b*16] - p0;
  for(int j=tid; j<cntb; j+=256){
    int2 pr = epairs[p0 + j];
    int pos = atomicAdd(&fillLoc[pr.y - n0], 1);
    esrc[pos] = pr.x;
  }
  __syncthreads();
  for(int i=tid; i<nmax; i+=256){
    int end = rp[n0+i+1];
    for(int j=fillLoc[i]; j<end; j++) esrc[j] = NN;
  }
}

// zero pad rows: Hx row NN (128), X3p row NN (64), Z row NN (256)
__global__ void k_zeropad(unsigned short* __restrict__ Hx, unsigned short* __restrict__ X3p,
                          unsigned short* __restrict__ Z){
  int t = threadIdx.x;
  if(t<128) Hx[(size_t)NN*128 + t] = 0;
  if(t<64)  X3p[(size_t)NN*64 + t] = 0;
  Z[(size_t)NN*256 + t] = 0;
}

// ---------------- elementwise / weight prep ----------------

__global__ void k_scale_x(const float* __restrict__ x, const float* __restrict__ norm,
                          unsigned short* __restrict__ H, int total){
  int i = blockIdx.x*blockDim.x + threadIdx.x;
  if(i<total) H[i] = f2bf(x[i] * norm[i>>7]);   // 128 feats/row
}

// W (K x N fp32) -> Wt (N x K bf16)
__global__ void k_wprep(const float* __restrict__ W, unsigned short* __restrict__ Wt, int K, int N){
  int i = blockIdx.x*blockDim.x + threadIdx.x;
  if(i < K*N){
    int k = i / N, n = i - k*N;
    Wt[(size_t)n*K + k] = f2bf(W[i]);
  }
}

// W3 (256 x 40 fp32) -> Wt3 (64 x 256 bf16), rows >= 40 zero
__global__ void k_wprep3(const float* __restrict__ W3, unsigned short* __restrict__ Wt){
  int i = blockIdx.x*blockDim.x + threadIdx.x;
  if(i < 64*256){
    int n = i >> 8, k = i & 255;
    Wt[i] = (n < 40) ? f2bf(W3[(size_t)k*40 + n]) : (unsigned short)0;
  }
}

// ---------------- BN finalize ----------------

__global__ void k_bnfin(const float* __restrict__ sums, const float* __restrict__ gamma,
                        const float* __restrict__ beta, float* __restrict__ scsh, int M){
  int c = threadIdx.x;
  float mean = sums[c]/(float)M;
  float var  = sums[256+c]/(float)M - mean*mean;
  float sc = gamma[c]*rsqrtf(var + BN_EPS);
  scsh[c] = sc;
  scsh[256+c] = beta[c] - mean*sc;
}

// ---------------- aggregation (wave per node, padded CSR) ----------------

__global__ __launch_bounds__(64) void k_agg128(const unsigned short* __restrict__ H,
    const int* __restrict__ rp, const int* __restrict__ esrc,
    const float* __restrict__ norm, unsigned short* __restrict__ out){
  int node = blockIdx.x, lane = threadIdx.x;
  int s0 = rp[node], s1 = rp[node+1];
  float a0=0.f, a1=0.f;
  for(int e=s0; e<s1; e+=4){
    int4 cur = *(const int4*)(esrc+e);
    unsigned v0 = *(const unsigned*)(H + (size_t)cur.x*128 + lane*2);
    unsigned v1 = *(const unsigned*)(H + (size_t)cur.y*128 + lane*2);
    unsigned v2 = *(const unsigned*)(H + (size_t)cur.z*128 + lane*2);
    unsigned v3 = *(const unsigned*)(H + (size_t)cur.w*128 + lane*2);
    a0 += bflo(v0)+bflo(v1)+bflo(v2)+bflo(v3);
    a1 += bfhi(v0)+bfhi(v1)+bfhi(v2)+bfhi(v3);
  }
  float nn = norm[node];
  *(unsigned*)(out + (size_t)node*128 + lane*2) = pk2(a0*nn, a1*nn);
}

// layer-2 aggregation with BN+ReLU+norm[src] fused into the gather.
// reads raw Z1 (bf16, pre-BN, zero row NN); lane owns cols lane*4..lane*4+3.
__global__ __launch_bounds__(64) void k_agg256f(const unsigned short* __restrict__ Z,
    const int* __restrict__ rp, const int* __restrict__ esrc,
    const float* __restrict__ norm, const float* __restrict__ scsh,
    unsigned short* __restrict__ out){
  int node = blockIdx.x, lane = threadIdx.x;
  float4 sc = *(const float4*)(scsh + lane*4);
  float4 sh = *(const float4*)(scsh + 256 + lane*4);
  int s0 = rp[node], s1 = rp[node+1];
  float a0=0.f,a1=0.f,a2=0.f,a3=0.f;
  for(int e=s0; e<s1; e+=4){
    int4 cur = *(const int4*)(esrc+e);
    float n0=norm[cur.x], n1=norm[cur.y], n2=norm[cur.z], n3=norm[cur.w];
    uint2 va = *(const uint2*)(Z + (size_t)cur.x*256 + lane*4);
    uint2 vb = *(const uint2*)(Z + (size_t)cur.y*256 + lane*4);
    uint2 vc = *(const uint2*)(Z + (size_t)cur.z*256 + lane*4);
    uint2 vd = *(const uint2*)(Z + (size_t)cur.w*256 + lane*4);
    a0 += fmaxf(bflo(va.x)*sc.x+sh.x,0.f)*n0 + fmaxf(bflo(vb.x)*sc.x+sh.x,0.f)*n1
        + fmaxf(bflo(vc.x)*sc.x+sh.x,0.f)*n2 + fmaxf(bflo(vd.x)*sc.x+sh.x,0.f)*n3;
    a1 += fmaxf(bfhi(va.x)*sc.y+sh.y,0.f)*n0 + fmaxf(bfhi(vb.x)*sc.y+sh.y,0.f)*n1
        + fmaxf(bfhi(vc.x)*sc.y+sh.y,0.f)*n2 + fmaxf(bfhi(vd.x)*sc.y+sh.y,0.f)*n3;
    a2 += fmaxf(bflo(va.y)*sc.z+sh.z,0.f)*n0 + fmaxf(bflo(vb.y)*sc.z+sh.z,0.f)*n1
        + fmaxf(bflo(vc.y)*sc.z+sh.z,0.f)*n2 + fmaxf(bflo(vd.y)*sc.z+sh.z,0.f)*n3;
    a3 += fmaxf(bfhi(va.y)*sc.w+sh.w,0.f)*n0 + fmaxf(bfhi(vb.y)*sc.w+sh.w,0.f)*n1
        + fmaxf(bfhi(vc.y)*sc.w+sh.w,0.f)*n2 + fmaxf(bfhi(vd.y)*sc.w+sh.w,0.f)*n3;
  }
  float nn = norm[node];
  uint2 pkk;
  pkk.x = pk2(a0*nn, a1*nn);
  pkk.y = pk2(a2*nn, a3*nn);
  *(uint2*)(out + (size_t)node*256 + lane*4) = pkk;
}

// final aggregation: X3p rows 64 bf16 (cols 40-63 zero). 8 edges/iter, uint4/lane.
__global__ __launch_bounds__(64) void k_agg64(const unsigned short* __restrict__ X3p,
    const int* __restrict__ rp, const int* __restrict__ esrc,
    const float* __restrict__ norm, const float* __restrict__ b3,
    float* __restrict__ out){
  int node = blockIdx.x, lane = threadIdx.x;
  int s0 = rp[node], s1 = rp[node+1];
  int es = lane >> 3, s = lane & 7;
  float a[8] = {};
  for(int e=s0; e<s1; e+=8){
    int4 A4 = *(const int4*)(esrc+e);
    int4 B4 = *(const int4*)(esrc+e+4);
    int idx = es==0?A4.x: es==1?A4.y: es==2?A4.z: es==3?A4.w:
              es==4?B4.x: es==5?B4.y: es==6?B4.z: B4.w;
    uint4 v = *(const uint4*)(X3p + (size_t)idx*64 + s*8);
    a[0]+=bflo(v.x); a[1]+=bfhi(v.x); a[2]+=bflo(v.y); a[3]+=bfhi(v.y);
    a[4]+=bflo(v.z); a[5]+=bfhi(v.z); a[6]+=bflo(v.w); a[7]+=bfhi(v.w);
  }
  #pragma unroll
  for(int off=8; off<64; off<<=1){
    #pragma unroll
    for(int j=0;j<8;j++) a[j] += __shfl_xor(a[j], off, 64);
  }
  bool act = s < 5;   // cols s*8..s*8+7 < 40
  float nn = norm[node];
  float bv[8] = {};
  if(act){
    float4 t0 = *(const float4*)(b3 + s*8);
    float4 t1 = *(const float4*)(b3 + s*8 + 4);
    bv[0]=t0.x; bv[1]=t0.y; bv[2]=t0.z; bv[3]=t0.w;
    bv[4]=t1.x; bv[5]=t1.y; bv[6]=t1.z; bv[7]=t1.w;
  }
  float v[8];
  float mx = -INFINITY;
  #pragma unroll
  for(int j=0;j<8;j++){
    v[j] = act ? (a[j]*nn + bv[j]) : -INFINITY;
    mx = fmaxf(mx, v[j]);
  }
  #pragma unroll
  for(int off=32; off; off>>=1) mx = fmaxf(mx, __shfl_xor(mx, off, 64));
  float sum = 0.f;
  if(act && es==0){
    #pragma unroll
    for(int j=0;j<8;j++) sum += expf(v[j]-mx);
  }
  #pragma unroll
  for(int off=32; off; off>>=1) sum += __shfl_xor(sum, off, 64);
  float lse = logf(sum);
  if(act && es==0){
    float4 o0, o1;
    o0.x=v[0]-mx-lse; o0.y=v[1]-mx-lse; o0.z=v[2]-mx-lse; o0.w=v[3]-mx-lse;
    o1.x=v[4]-mx-lse; o1.y=v[5]-mx-lse; o1.z=v[6]-mx-lse; o1.w=v[7]-mx-lse;
    *(float4*)(out + (size_t)node*40 + s*8) = o0;
    *(float4*)(out + (size_t)node*40 + s*8 + 4) = o1;
  }
}

// ---------------- MFMA GEMM: C = A*Bt^T + bias (bf16 out) + fused column stats ----------------

__global__ __launch_bounds__(256) void k_mgemm(
    const unsigned short* __restrict__ A, const unsigned short* __restrict__ Bt,
    const float* __restrict__ bias, unsigned short* __restrict__ C,
    float* __restrict__ sums, int M, int K, int Nn){
  __shared__ unsigned short As[128*64];
  __shared__ unsigned short Bs[128*64];
  int nt = Nn >> 7;
  int bm = blockIdx.x / nt, bn = blockIdx.x % nt;
  int m0 = bm*128, n0 = bn*128;
  int tid = threadIdx.x;
  int wave = tid >> 6, lane = tid & 63;
  int wm = (wave>>1)*64, wn = (wave&1)*64;
  int lrow = lane & 15, lq = lane >> 4;
  int srow = lane >> 3;
  int sx = ((lane & 7) ^ srow) * 8;
  f32x4 acc[4][4] = {};
  for(int k0=0; k0<K; k0+=64){
    __syncthreads();
    #pragma unroll
    for(int c4=0;c4<4;c4++){
      int c = wave*4 + c4;
      int grow = c*8 + srow;
      const unsigned short* ga = A + (size_t)(m0+grow)*K + k0 + sx;
      __builtin_amdgcn_global_load_lds((const __attribute__((address_space(1))) void*)ga,
          (__attribute__((address_space(3))) void*)(As + (size_t)c*512), 16, 0, 0);
      const unsigned short* gb = Bt + (size_t)(n0+grow)*K + k0 + sx;
      __builtin_amdgcn_global_load_lds((const __attribute__((address_space(1))) void*)gb,
          (__attribute__((address_space(3))) void*)(Bs + (size_t)c*512), 16, 0, 0);
    }
    __syncthreads();
    #pragma unroll
    for(int kk=0;kk<2;kk++){
      short8 af[4], bf[4];
      #pragma unroll
      for(int i=0;i<4;i++){
        int Ra = wm + i*16 + lrow;
        int ca = (kk*4 + lq) ^ (Ra & 7);
        af[i] = *(const short8*)(As + Ra*64 + ca*8);
        int Rb = wn + i*16 + lrow;
        int cb = (kk*4 + lq) ^ (Rb & 7);
        bf[i] = *(const short8*)(Bs + Rb*64 + cb*8);
      }
      #pragma unroll
      for(int i=0;i<4;i++)
        #pragma unroll
        for(int j=0;j<4;j++)
          acc[i][j] = __builtin_amdgcn_mfma_f32_16x16x32_bf16(af[i], bf[j], acc[i][j], 0, 0, 0);
    }
  }
  // epilogue: write C (bf16) and accumulate column sum/sumsq for BN stats
  #pragma unroll
  for(int j=0;j<4;j++){
    int col = n0 + wn + j*16 + lrow;
    float bj = bias[col];
    float s=0.f, s2=0.f;
    #pragma unroll
    for(int i=0;i<4;i++){
      #pragma unroll
      for(int r=0;r<4;r++){
        int row = m0 + wm + i*16 + lq*4 + r;
        if(row < M){
          float v = acc[i][j][r] + bj;
          s += v; s2 += v*v;
          C[(size_t)row*Nn + col] = f2bf(v);
        }
      }
    }
    s  += __shfl_xor(s, 16, 64);  s  += __shfl_xor(s, 32, 64);
    s2 += __shfl_xor(s2, 16, 64); s2 += __shfl_xor(s2, 32, 64);
    if(lq == 0){
      atomicAdd(&sums[col], s);
      atomicAdd(&sums[256+col], s2);
    }
  }
}

// layer-3: 128x64 tile; A-staging applies BN+ReLU (scsh) on the fly (reg->LDS);
// out X3p bf16 stride 64 (*rownorm). Bt = Wt3 (64 x K).
__global__ __launch_bounds__(256) void k_mgemm3(
    const unsigned short* __restrict__ Zin, const unsigned short* __restrict__ Bt,
    const float* __restrict__ scsh, const float* __restrict__ rownorm,
    unsigned short* __restrict__ X3p, int M, int K){
  __shared__ unsigned short As[128*64];
  __shared__ unsigned short Bs[64*64];
  int m0 = blockIdx.x*128;
  int tid = threadIdx.x;
  int wave = tid >> 6, lane = tid & 63;
  int wm = wave*32;
  int lrow = lane & 15, lq = lane >> 4;
  int srow = lane >> 3;
  int sx = ((lane & 7) ^ srow) * 8;
  f32x4 acc[2][4] = {};
  for(int k0=0; k0<K; k0+=64){
    // prefetch raw A (pre-BN Z2) to regs while previous iter computes
    uint4 raw[4];
    #pragma unroll
    for(int c4=0;c4<4;c4++){
      int c = wave*4 + c4;
      int grow = c*8 + srow;
      raw[c4] = *(const uint4*)(Zin + (size_t)(m0+grow)*K + k0 + sx);
    }
    float4 sc0 = *(const float4*)(scsh + k0 + sx);
    float4 sc1 = *(const float4*)(scsh + k0 + sx + 4);
    float4 sh0 = *(const float4*)(scsh + 256 + k0 + sx);
    float4 sh1 = *(const float4*)(scsh + 256 + k0 + sx + 4);
    __syncthreads();                 // previous iter's LDS reads done
    #pragma unroll
    for(int c4=0;c4<4;c4++){
      int c = wave*4 + c4;
      uint4 w;
      w.x = pk2(fmaxf(bflo(raw[c4].x)*sc0.x+sh0.x,0.f), fmaxf(bfhi(raw[c4].x)*sc0.y+sh0.y,0.f));
      w.y = pk2(fmaxf(bflo(raw[c4].y)*sc0.z+sh0.z,0.f), fmaxf(bfhi(raw[c4].y)*sc0.w+sh0.w,0.f));
      w.z = pk2(fmaxf(bflo(raw[c4].z)*sc1.x+sh1.x,0.f), fmaxf(bfhi(raw[c4].z)*sc1.y+sh1.y,0.f));
      w.w = pk2(fmaxf(bflo(raw[c4].w)*sc1.z+sh1.z,0.f), fmaxf(bfhi(raw[c4].w)*sc1.w+sh1.w,0.f));
      *(uint4*)(As + (size_t)c*512 + (size_t)lane*8) = w;
    }
    #pragma unroll
    for(int c4=0;c4<2;c4++){
      int c = wave*2 + c4;
      int grow = c*8 + srow;            // 0..63
      const unsigned short* gb = Bt + (size_t)grow*K + k0 + sx;
      __builtin_amdgcn_global_load_lds((const __attribute__((address_space(1))) void*)gb,
          (__attribute__((address_space(3))) void*)(Bs + (size_t)c*512), 16, 0, 0);
    }
    __syncthreads();
    #pragma unroll
    for(int kk=0;kk<2;kk++){
      short8 af[2], bf[4];
      #pragma unroll
      for(int i=0;i<2;i++){
        int Ra = wm + i*16 + lrow;
        int ca = (kk*4 + lq) ^ (Ra & 7);
        af[i] = *(const short8*)(As + Ra*64 + ca*8);
      }
      #pragma unroll
      for(int j=0;j<4;j++){
        int Rb = j*16 + lrow;
        int cb = (kk*4 + lq) ^ (Rb & 7);
        bf[j] = *(const short8*)(Bs + Rb*64 + cb*8);
      }
      #pragma unroll
      for(int i=0;i<2;i++)
        #pragma unroll
        for(int j=0;j<4;j++)
          acc[i][j] = __builtin_amdgcn_mfma_f32_16x16x32_bf16(af[i], bf[j], acc[i][j], 0, 0, 0);
    }
  }
  #pragma unroll
  for(int j=0;j<4;j++){
    int col = j*16 + lrow;
    #pragma unroll
    for(int i=0;i<2;i++){
      #pragma unroll
      for(int r=0;r<4;r++){
        int row = m0 + wm + i*16 + lq*4 + r;
        if(row < M) X3p[(size_t)row*64 + col] = f2bf(acc[i][j][r] * rownorm[row]);
      }
    }
  }
}

// ---------------- launch ----------------

extern "C" void kernel_launch(void* const* d_in, const int* in_sizes, int n_in,
                              void* d_out, int out_size, void* d_ws, size_t ws_size,
                              hipStream_t stream){
  const float* x   = (const float*)d_in[0];
  const int*   src = (const int*)d_in[1];
  const int*   dst = (const int*)d_in[2];
  const float* W1  = (const float*)d_in[3];
  const float* b1  = (const float*)d_in[4];
  const float* g1  = (const float*)d_in[5];
  const float* be1 = (const float*)d_in[6];
  const float* W2  = (const float*)d_in[7];
  const float* b2  = (const float*)d_in[8];
  const float* g2  = (const float*)d_in[9];
  const float* be2 = (const float*)d_in[10];
  const float* W3  = (const float*)d_in[11];
  const float* b3  = (const float*)d_in[12];
  float* out = (float*)d_out;
  const int N = NN;
  const int E = in_sizes[1];

  char* p = (char*)d_ws;
  size_t off = 0;
  auto alloc = [&](size_t bytes)->void*{
    void* r = p + off;
    off += (bytes + 511) & ~(size_t)511;
    return r;
  };
  // Footprint ~184 MB — under the ~229 MB known-good high-water mark.
  // (ws crash forensics: 270 MB crash / 219 pass / 229 pass / 235 crash.)
  int*   cnt   = (int*)  alloc((size_t)N*4);
  float* sums1 = (float*)alloc(2048);
  float* sums2 = (float*)alloc(2048);
  size_t zero_bytes = off;                       // cnt|sums zeroed each call
  int*   rp    = (int*)  alloc((size_t)(N+1)*4);
  float* norm  = (float*)alloc((size_t)(N+1)*4);
  float* scsh1 = (float*)alloc(2048);
  float* scsh2 = (float*)alloc(2048);
  int*   bfill = (int*)  alloc((size_t)NBUCK*16*4);                  // line-padded
  unsigned short* Wt1 = (unsigned short*)alloc((size_t)256*128*2);
  unsigned short* Wt2 = (unsigned short*)alloc((size_t)256*256*2);
  unsigned short* Wt3 = (unsigned short*)alloc((size_t)64*256*2);
  int*   esrc  = (int*)  alloc((size_t)(E + 7*N + 16)*4);            // pad-8 CSR
  unsigned short* Hx  = (unsigned short*)alloc((size_t)(N+1)*128*2); // x*norm + zero row
  unsigned short* M1  = (unsigned short*)alloc((size_t)N*128*2);     // agg128 out
  unsigned short* Mb2 = (unsigned short*)alloc((size_t)N*256*2);     // agg256f out
  unsigned short* Z   = (unsigned short*)alloc((size_t)(N+1)*256*2); // mgemm out + zero row
  unsigned short* X3p = (unsigned short*)alloc((size_t)(N+1)*64*2);  // layer-3 proj (64-col)
  // epairs (bucketed (src,dst) pairs, <=31.3MB) aliases Mb2 (51.2MB): dead
  // before k_agg256f writes Mb2 on this single stream.
  int2* epairs = (int2*)Mb2;
  (void)ws_size; (void)n_in; (void)out_size;

  hipMemsetAsync(d_ws, 0, zero_bytes, stream);

  k_hist   <<<(E+255)/256,256,0,stream>>>(dst, cnt, E);
  k_norm   <<<(N+256)/256,256,0,stream>>>(cnt, norm, N);
  k_scan   <<<1,1024,0,stream>>>(cnt, rp, N);
  k_binit  <<<(NBUCK+255)/256,256,0,stream>>>(rp, bfill);
  k_bucket1<<<(E+T1_TILE-1)/T1_TILE,256,0,stream>>>(src, dst, bfill, epairs, E);
  k_bucket2<<<NBUCK,256,0,stream>>>(epairs, bfill, rp, esrc);
  k_zeropad<<<1,256,0,stream>>>(Hx, X3p, Z);
  k_wprep  <<<(128*256+255)/256,256,0,stream>>>(W1, Wt1, 128, 256);
  k_wprep  <<<(256*256+255)/256,256,0,stream>>>(W2, Wt2, 256, 256);
  k_wprep3 <<<(64*256+255)/256,256,0,stream>>>(W3, Wt3);

  // layer 1: Hx = x*norm -> agg128*norm -> MFMA @W1+b1 (+stats) -> Z1(bf16)
  k_scale_x<<<(N*128+255)/256,256,0,stream>>>(x, norm, Hx, N*128);
  k_agg128 <<<N,64,0,stream>>>(Hx, rp, esrc, norm, M1);
  k_mgemm  <<<((N+127)/128)*2,256,0,stream>>>(M1, Wt1, b1, Z, sums1, N, 128, 256);
  k_bnfin  <<<1,256,0,stream>>>(sums1, g1, be1, scsh1, N);

  // layer 2: agg256 fused BN+ReLU+norm[src] on Z1 -> MFMA @W2+b2 (+stats) -> Z2
  k_agg256f<<<N,64,0,stream>>>(Z, rp, esrc, norm, scsh1, Mb2);
  k_mgemm  <<<((N+127)/128)*2,256,0,stream>>>(Mb2, Wt2, b2, Z, sums2, N, 256, 256);
  k_bnfin  <<<1,256,0,stream>>>(sums2, g2, be2, scsh2, N);

  // layer 3: mgemm3 applies BN+ReLU to Z2 in staging, X3p = (relu(bn(Z2))@W3p)*norm
  k_mgemm3 <<<(N+127)/128,256,0,stream>>>(Z, Wt3, scsh2, norm, X3p, N, 256);
  k_agg64  <<<N,64,0,stream>>>(X3p, rp, esrc, norm, b3, out);
}

// Round 2
// 1101.547 us; speedup vs baseline: 1.1752x; 1.0029x over previous
//
#include <hip/hip_runtime.h>
#include <cstdint>
#include <cstddef>

#define NN 100000
#define BN_EPS 1e-5f

// bucketed CSR build: 128 nodes per bucket
#define NB_SHIFT 7
#define NBUCK ((NN >> NB_SHIFT) + 1)   // 782
#define T1_EPT 16
#define T1_TILE (256*T1_EPT)           // 4096 edges per pass-1 block

typedef __attribute__((ext_vector_type(8))) short short8;
typedef __attribute__((ext_vector_type(4))) float f32x4;

static __device__ __forceinline__ float bflo(unsigned u){ return __uint_as_float(u<<16); }
static __device__ __forceinline__ float bfhi(unsigned u){ return __uint_as_float(u & 0xFFFF0000u); }
static __device__ __forceinline__ unsigned short f2bf(float f){
  unsigned u = __float_as_uint(f);
  u += 0x7FFFu + ((u>>16)&1u);   // round-to-nearest-even
  return (unsigned short)(u>>16);
}
static __device__ __forceinline__ unsigned pk2(float a, float b){
  return (unsigned)f2bf(a) | ((unsigned)f2bf(b) << 16);
}

// ---------------- graph prep ----------------

__global__ void k_hist(const int* __restrict__ dst, int* __restrict__ cnt, int E){
  int e = blockIdx.x*blockDim.x + threadIdx.x;
  if(e<E) atomicAdd(&cnt[dst[e]], 1);
}

// norm over N+1: norm[NN] = 0 (zero row / pad-edge killer)
__global__ void k_norm(const int* __restrict__ cnt, float* __restrict__ norm, int n){
  int i = blockIdx.x*blockDim.x + threadIdx.x;
  if(i<=n) norm[i] = (i==n) ? 0.f : rsqrtf(fmaxf((float)cnt[i], 1.0f));
}

// exclusive scan over counts padded to multiple of 8
__global__ __launch_bounds__(1024) void k_scan(const int* __restrict__ cnt, int* __restrict__ rp, int n){
  __shared__ int sm[1024];
  int t = threadIdx.x;
  int chunk = (n + 1023)/1024;
  int lo = t*chunk, hi = min(lo+chunk, n);
  int s=0;
  for(int i=lo;i<hi;i++) s += (cnt[i]+7)&~7;
  sm[t]=s; __syncthreads();
  for(int off=1; off<1024; off<<=1){
    int v = (t>=off)? sm[t-off] : 0;
    __syncthreads();
    sm[t]+=v;
    __syncthreads();
  }
  int run = sm[t]-s;
  for(int i=lo;i<hi;i++){ rp[i]=run; run+=(cnt[i]+7)&~7; }
  if(t==1023) rp[n]=sm[1023];
}

// bucket fill pointers: one counter per 64B line (stride 16)
__global__ void k_binit(const int* __restrict__ rp, int* __restrict__ bfill){
  int b = blockIdx.x*blockDim.x + threadIdx.x;
  if(b<NBUCK) bfill[b*16] = rp[min(b<<NB_SHIFT, NN)];
}

// pass 1: partition edges into NBUCK per-dst-range buckets of (src,dst) pairs.
__global__ __launch_bounds__(256) void k_bucket1(const int* __restrict__ src,
    const int* __restrict__ dst, int* __restrict__ bfill,
    int2* __restrict__ epairs, int E){
  __shared__ int hist[NBUCK];
  int tid = threadIdx.x;
  for(int j=tid; j<NBUCK; j+=256) hist[j]=0;
  __syncthreads();
  int base = blockIdx.x*T1_TILE;
  int s[T1_EPT], d[T1_EPT], r[T1_EPT];
  #pragma unroll
  for(int i=0;i<T1_EPT;i++){
    int e = base + i*256 + tid;
    if(e<E){
      s[i]=src[e]; d[i]=dst[e];
      r[i]=atomicAdd(&hist[d[i]>>NB_SHIFT], 1);
    }
  }
  __syncthreads();
  for(int j=tid; j<NBUCK; j+=256){
    int h = hist[j];
    if(h>0) hist[j] = atomicAdd(&bfill[j*16], h);   // replace count with global base
  }
  __syncthreads();
  #pragma unroll
  for(int i=0;i<T1_EPT;i++){
    int e = base + i*256 + tid;
    if(e<E){
      int pos = hist[d[i]>>NB_SHIFT] + r[i];
      epairs[pos] = make_int2(s[i], d[i]);
    }
  }
}

// pass 2: one block per bucket; LDS-atomic placement; writes pad slots (NN).
__global__ __launch_bounds__(256) void k_bucket2(const int2* __restrict__ epairs,
    const int* __restrict__ bfill, const int* __restrict__ rp,
    int* __restrict__ esrc){
  __shared__ int fillLoc[1<<NB_SHIFT];
  int b = blockIdx.x, tid = threadIdx.x;
  int n0 = b << NB_SHIFT;
  int nmax = min(1<<NB_SHIFT, NN - n0);
  for(int i=tid; i<nmax; i+=256) fillLoc[i] = rp[n0+i];
  __syncthreads();
  int p0 = rp[n0];
  int cntb = bfill[b*16] - p0;
  for(int j=tid; j<cntb; j+=256){
    int2 pr = epairs[p0 + j];
    int pos = atomicAdd(&fillLoc[pr.y - n0], 1);
    esrc[pos] = pr.x;
  }
  __syncthreads();
  for(int i=tid; i<nmax; i+=256){
    int end = rp[n0+i+1];
    for(int j=fillLoc[i]; j<end; j++) esrc[j] = NN;
  }
}

// zero pad rows: Hx row NN (128), X3p row NN (64), Z row NN (256)
__global__ void k_zeropad(unsigned short* __restrict__ Hx, unsigned short* __restrict__ X3p,
                          unsigned short* __restrict__ Z){
  int t = threadIdx.x;
  if(t<128) Hx[(size_t)NN*128 + t] = 0;
  if(t<64)  X3p[(size_t)NN*64 + t] = 0;
  Z[(size_t)NN*256 + t] = 0;
}

// ---------------- elementwise / weight prep ----------------

// x*norm -> bf16, float4/lane (4 elems), 32 float4 per 128-col row
__global__ void k_scale_x4(const float* __restrict__ x, const float* __restrict__ norm,
                           unsigned short* __restrict__ H, int total4){
  int i = blockIdx.x*blockDim.x + threadIdx.x;
  if(i<total4){
    float4 v = *(const float4*)(x + (size_t)i*4);
    float nn = norm[i>>5];
    uint2 w;
    w.x = pk2(v.x*nn, v.y*nn);
    w.y = pk2(v.z*nn, v.w*nn);
    *(uint2*)(H + (size_t)i*4) = w;
  }
}

// H2 = relu(bn(Z1)) * norm[row], bf16, over N+1 rows (row NN -> 0 via norm=0).
// uint4/thread = 8 elems; 32 threads per 256-col row.
__global__ void k_bnrelu(const unsigned short* __restrict__ Z, const float* __restrict__ scsh,
                         const float* __restrict__ norm, unsigned short* __restrict__ H2,
                         int total4){
  int i = blockIdx.x*blockDim.x + threadIdx.x;
  if(i<total4){
    int c8 = (i & 31) * 8;
    float nn = norm[i>>5];
    uint4 v = *(const uint4*)(Z + (size_t)i*8);
    float4 sc0 = *(const float4*)(scsh + c8);
    float4 sc1 = *(const float4*)(scsh + c8 + 4);
    float4 sh0 = *(const float4*)(scsh + 256 + c8);
    float4 sh1 = *(const float4*)(scsh + 256 + c8 + 4);
    uint4 w;
    w.x = pk2(fmaxf(bflo(v.x)*sc0.x+sh0.x,0.f)*nn, fmaxf(bfhi(v.x)*sc0.y+sh0.y,0.f)*nn);
    w.y = pk2(fmaxf(bflo(v.y)*sc0.z+sh0.z,0.f)*nn, fmaxf(bfhi(v.y)*sc0.w+sh0.w,0.f)*nn);
    w.z = pk2(fmaxf(bflo(v.z)*sc1.x+sh1.x,0.f)*nn, fmaxf(bfhi(v.z)*sc1.y+sh1.y,0.f)*nn);
    w.w = pk2(fmaxf(bflo(v.w)*sc1.z+sh1.z,0.f)*nn, fmaxf(bfhi(v.w)*sc1.w+sh1.w,0.f)*nn);
    *(uint4*)(H2 + (size_t)i*8) = w;
  }
}

// W (K x N fp32) -> Wt (N x K bf16)
__global__ void k_wprep(const float* __restrict__ W, unsigned short* __restrict__ Wt, int K, int N){
  int i = blockIdx.x*blockDim.x + threadIdx.x;
  if(i < K*N){
    int k = i / N, n = i - k*N;
    Wt[(size_t)n*K + k] = f2bf(W[i]);
  }
}

// W3 (256 x 40 fp32) -> Wt3 (64 x 256 bf16), rows >= 40 zero
__global__ void k_wprep3(const float* __restrict__ W3, unsigned short* __restrict__ Wt){
  int i = blockIdx.x*blockDim.x + threadIdx.x;
  if(i < 64*256){
    int n = i >> 8, k = i & 255;
    Wt[i] = (n < 40) ? f2bf(W3[(size_t)k*40 + n]) : (unsigned short)0;
  }
}

// ---------------- BN finalize ----------------

__global__ void k_bnfin(const float* __restrict__ sums, const float* __restrict__ gamma,
                        const float* __restrict__ beta, float* __restrict__ scsh, int M){
  int c = threadIdx.x;
  float mean = sums[c]/(float)M;
  float var  = sums[256+c]/(float)M - mean*mean;
  float sc = gamma[c]*rsqrtf(var + BN_EPS);
  scsh[c] = sc;
  scsh[256+c] = beta[c] - mean*sc;
}

// ---------------- aggregation (wave per node, padded CSR, pure sum) ----------------

// 128-col rows (256B): 4 edge-groups x 16 lanes x uint4(16B). 8 edges/iter.
__global__ __launch_bounds__(64) void k_agg128(const unsigned short* __restrict__ H,
    const int* __restrict__ rp, const int* __restrict__ esrc,
    const float* __restrict__ norm, unsigned short* __restrict__ out){
  int node = blockIdx.x, lane = threadIdx.x;
  int s0 = rp[node], s1 = rp[node+1];
  int g = lane >> 4, c = lane & 15;
  float a[8] = {};
  for(int e=s0; e<s1; e+=8){
    int4 A4 = *(const int4*)(esrc+e);
    int4 B4 = *(const int4*)(esrc+e+4);
    int i0 = g==0?A4.x: g==1?A4.y: g==2?A4.z: A4.w;
    int i1 = g==0?B4.x: g==1?B4.y: g==2?B4.z: B4.w;
    uint4 v0 = *(const uint4*)(H + (size_t)i0*128 + c*8);
    uint4 v1 = *(const uint4*)(H + (size_t)i1*128 + c*8);
    a[0]+=bflo(v0.x)+bflo(v1.x); a[1]+=bfhi(v0.x)+bfhi(v1.x);
    a[2]+=bflo(v0.y)+bflo(v1.y); a[3]+=bfhi(v0.y)+bfhi(v1.y);
    a[4]+=bflo(v0.z)+bflo(v1.z); a[5]+=bfhi(v0.z)+bfhi(v1.z);
    a[6]+=bflo(v0.w)+bflo(v1.w); a[7]+=bfhi(v0.w)+bfhi(v1.w);
  }
  #pragma unroll
  for(int j=0;j<8;j++){
    a[j] += __shfl_xor(a[j], 16, 64);
    a[j] += __shfl_xor(a[j], 32, 64);
  }
  if(g==0){
    float nn = norm[node];
    uint4 w;
    w.x = pk2(a[0]*nn, a[1]*nn);
    w.y = pk2(a[2]*nn, a[3]*nn);
    w.z = pk2(a[4]*nn, a[5]*nn);
    w.w = pk2(a[6]*nn, a[7]*nn);
    *(uint4*)(out + (size_t)node*128 + c*8) = w;
  }
}

// 256-col rows (512B): 2 edge-groups x 32 lanes x uint4(16B). 8 edges/iter.
// input H2 is pre-scaled (BN+ReLU+norm fused out of the gather).
__global__ __launch_bounds__(64) void k_agg256(const unsigned short* __restrict__ H,
    const int* __restrict__ rp, const int* __restrict__ esrc,
    const float* __restrict__ norm, unsigned short* __restrict__ out){
  int node = blockIdx.x, lane = threadIdx.x;
  int s0 = rp[node], s1 = rp[node+1];
  int g = lane >> 5, c = lane & 31;
  float a[8] = {};
  for(int e=s0; e<s1; e+=8){
    int4 A4 = *(const int4*)(esrc+e);
    int4 B4 = *(const int4*)(esrc+e+4);
    int i0 = g ? A4.y : A4.x;
    int i1 = g ? A4.w : A4.z;
    int i2 = g ? B4.y : B4.x;
    int i3 = g ? B4.w : B4.z;
    uint4 v0 = *(const uint4*)(H + (size_t)i0*256 + c*8);
    uint4 v1 = *(const uint4*)(H + (size_t)i1*256 + c*8);
    uint4 v2 = *(const uint4*)(H + (size_t)i2*256 + c*8);
    uint4 v3 = *(const uint4*)(H + (size_t)i3*256 + c*8);
    a[0]+=bflo(v0.x)+bflo(v1.x)+bflo(v2.x)+bflo(v3.x);
    a[1]+=bfhi(v0.x)+bfhi(v1.x)+bfhi(v2.x)+bfhi(v3.x);
    a[2]+=bflo(v0.y)+bflo(v1.y)+bflo(v2.y)+bflo(v3.y);
    a[3]+=bfhi(v0.y)+bfhi(v1.y)+bfhi(v2.y)+bfhi(v3.y);
    a[4]+=bflo(v0.z)+bflo(v1.z)+bflo(v2.z)+bflo(v3.z);
    a[5]+=bfhi(v0.z)+bfhi(v1.z)+bfhi(v2.z)+bfhi(v3.z);
    a[6]+=bflo(v0.w)+bflo(v1.w)+bflo(v2.w)+bflo(v3.w);
    a[7]+=bfhi(v0.w)+bfhi(v1.w)+bfhi(v2.w)+bfhi(v3.w);
  }
  #pragma unroll
  for(int j=0;j<8;j++) a[j] += __shfl_xor(a[j], 32, 64);
  if(g==0){
    float nn = norm[node];
    uint4 w;
    w.x = pk2(a[0]*nn, a[1]*nn);
    w.y = pk2(a[2]*nn, a[3]*nn);
    w.z = pk2(a[4]*nn, a[5]*nn);
    w.w = pk2(a[6]*nn, a[7]*nn);
    *(uint4*)(out + (size_t)node*256 + c*8) = w;
  }
}

// final aggregation: X3p rows 64 bf16 (cols 40-63 zero). 8 edges/iter, uint4/lane.
__global__ __launch_bounds__(64) void k_agg64(const unsigned short* __restrict__ X3p,
    const int* __restrict__ rp, const int* __restrict__ esrc,
    const float* __restrict__ norm, const float* __restrict__ b3,
    float* __restrict__ out){
  int node = blockIdx.x, lane = threadIdx.x;
  int s0 = rp[node], s1 = rp[node+1];
  int es = lane >> 3, s = lane & 7;
  float a[8] = {};
  for(int e=s0; e<s1; e+=8){
    int4 A4 = *(const int4*)(esrc+e);
    int4 B4 = *(const int4*)(esrc+e+4);
    int idx = es==0?A4.x: es==1?A4.y: es==2?A4.z: es==3?A4.w:
              es==4?B4.x: es==5?B4.y: es==6?B4.z: B4.w;
    uint4 v = *(const uint4*)(X3p + (size_t)idx*64 + s*8);
    a[0]+=bflo(v.x); a[1]+=bfhi(v.x); a[2]+=bflo(v.y); a[3]+=bfhi(v.y);
    a[4]+=bflo(v.z); a[5]+=bfhi(v.z); a[6]+=bflo(v.w); a[7]+=bfhi(v.w);
  }
  #pragma unroll
  for(int off=8; off<64; off<<=1){
    #pragma unroll
    for(int j=0;j<8;j++) a[j] += __shfl_xor(a[j], off, 64);
  }
  bool act = s < 5;   // cols s*8..s*8+7 < 40
  float nn = norm[node];
  float bv[8] = {};
  if(act){
    float4 t0 = *(const float4*)(b3 + s*8);
    float4 t1 = *(const float4*)(b3 + s*8 + 4);
    bv[0]=t0.x; bv[1]=t0.y; bv[2]=t0.z; bv[3]=t0.w;
    bv[4]=t1.x; bv[5]=t1.y; bv[6]=t1.z; bv[7]=t1.w;
  }
  float v[8];
  float mx = -INFINITY;
  #pragma unroll
  for(int j=0;j<8;j++){
    v[j] = act ? (a[j]*nn + bv[j]) : -INFINITY;
    mx = fmaxf(mx, v[j]);
  }
  #pragma unroll
  for(int off=32; off; off>>=1) mx = fmaxf(mx, __shfl_xor(mx, off, 64));
  float sum = 0.f;
  if(act && es==0){
    #pragma unroll
    for(int j=0;j<8;j++) sum += expf(v[j]-mx);
  }
  #pragma unroll
  for(int off=32; off; off>>=1) sum += __shfl_xor(sum, off, 64);
  float lse = logf(sum);
  if(act && es==0){
    float4 o0, o1;
    o0.x=v[0]-mx-lse; o0.y=v[1]-mx-lse; o0.z=v[2]-mx-lse; o0.w=v[3]-mx-lse;
    o1.x=v[4]-mx-lse; o1.y=v[5]-mx-lse; o1.z=v[6]-mx-lse; o1.w=v[7]-mx-lse;
    *(float4*)(out + (size_t)node*40 + s*8) = o0;
    *(float4*)(out + (size_t)node*40 + s*8 + 4) = o1;
  }
}

// ---------------- MFMA GEMM: C = A*Bt^T + bias (bf16 out) + fused column stats ----------------

__global__ __launch_bounds__(256) void k_mgemm(
    const unsigned short* __restrict__ A, const unsigned short* __restrict__ Bt,
    const float* __restrict__ bias, unsigned short* __restrict__ C,
    float* __restrict__ sums, int M, int K, int Nn){
  __shared__ unsigned short As[128*64];
  __shared__ unsigned short Bs[128*64];
  int nt = Nn >> 7;
  int bm = blockIdx.x / nt, bn = blockIdx.x % nt;
  int m0 = bm*128, n0 = bn*128;
  int tid = threadIdx.x;
  int wave = tid >> 6, lane = tid & 63;
  int wm = (wave>>1)*64, wn = (wave&1)*64;
  int lrow = lane & 15, lq = lane >> 4;
  int srow = lane >> 3;
  int sx = ((lane & 7) ^ srow) * 8;
  f32x4 acc[4][4] = {};
  for(int k0=0; k0<K; k0+=64){
    __syncthreads();
    #pragma unroll
    for(int c4=0;c4<4;c4++){
      int c = wave*4 + c4;
      int grow = c*8 + srow;
      const unsigned short* ga = A + (size_t)(m0+grow)*K + k0 + sx;
      __builtin_amdgcn_global_load_lds((const __attribute__((address_space(1))) void*)ga,
          (__attribute__((address_space(3))) void*)(As + (size_t)c*512), 16, 0, 0);
      const unsigned short* gb = Bt + (size_t)(n0+grow)*K + k0 + sx;
      __builtin_amdgcn_global_load_lds((const __attribute__((address_space(1))) void*)gb,
          (__attribute__((address_space(3))) void*)(Bs + (size_t)c*512), 16, 0, 0);
    }
    __syncthreads();
    #pragma unroll
    for(int kk=0;kk<2;kk++){
      short8 af[4], bf[4];
      #pragma unroll
      for(int i=0;i<4;i++){
        int Ra = wm + i*16 + lrow;
        int ca = (kk*4 + lq) ^ (Ra & 7);
        af[i] = *(const short8*)(As + Ra*64 + ca*8);
        int Rb = wn + i*16 + lrow;
        int cb = (kk*4 + lq) ^ (Rb & 7);
        bf[i] = *(const short8*)(Bs + Rb*64 + cb*8);
      }
      #pragma unroll
      for(int i=0;i<4;i++)
        #pragma unroll
        for(int j=0;j<4;j++)
          acc[i][j] = __builtin_amdgcn_mfma_f32_16x16x32_bf16(af[i], bf[j], acc[i][j], 0, 0, 0);
    }
  }
  // epilogue: write C (bf16) and accumulate column sum/sumsq for BN stats
  #pragma unroll
  for(int j=0;j<4;j++){
    int col = n0 + wn + j*16 + lrow;
    float bj = bias[col];
    float s=0.f, s2=0.f;
    #pragma unroll
    for(int i=0;i<4;i++){
      #pragma unroll
      for(int r=0;r<4;r++){
        int row = m0 + wm + i*16 + lq*4 + r;
        if(row < M){
          float v = acc[i][j][r] + bj;
          s += v; s2 += v*v;
          C[(size_t)row*Nn + col] = f2bf(v);
        }
      }
    }
    s  += __shfl_xor(s, 16, 64);  s  += __shfl_xor(s, 32, 64);
    s2 += __shfl_xor(s2, 16, 64); s2 += __shfl_xor(s2, 32, 64);
    if(lq == 0){
      atomicAdd(&sums[col], s);
      atomicAdd(&sums[256+col], s2);
    }
  }
}

// layer-3: 128x64 tile; A-staging applies BN+ReLU (scsh) on the fly (reg->LDS);
// out X3p bf16 stride 64 (*rownorm). Bt = Wt3 (64 x K).
__global__ __launch_bounds__(256) void k_mgemm3(
    const unsigned short* __restrict__ Zin, const unsigned short* __restrict__ Bt,
    const float* __restrict__ scsh, const float* __restrict__ rownorm,
    unsigned short* __restrict__ X3p, int M, int K){
  __shared__ unsigned short As[128*64];
  __shared__ unsigned short Bs[64*64];
  int m0 = blockIdx.x*128;
  int tid = threadIdx.x;
  int wave = tid >> 6, lane = tid & 63;
  int wm = wave*32;
  int lrow = lane & 15, lq = lane >> 4;
  int srow = lane >> 3;
  int sx = ((lane & 7) ^ srow) * 8;
  f32x4 acc[2][4] = {};
  for(int k0=0; k0<K; k0+=64){
    // prefetch raw A (pre-BN Z2) to regs while previous iter computes
    uint4 raw[4];
    #pragma unroll
    for(int c4=0;c4<4;c4++){
      int c = wave*4 + c4;
      int grow = c*8 + srow;
      raw[c4] = *(const uint4*)(Zin + (size_t)(m0+grow)*K + k0 + sx);
    }
    float4 sc0 = *(const float4*)(scsh + k0 + sx);
    float4 sc1 = *(const float4*)(scsh + k0 + sx + 4);
    float4 sh0 = *(const float4*)(scsh + 256 + k0 + sx);
    float4 sh1 = *(const float4*)(scsh + 256 + k0 + sx + 4);
    __syncthreads();                 // previous iter's LDS reads done
    #pragma unroll
    for(int c4=0;c4<4;c4++){
      int c = wave*4 + c4;
      uint4 w;
      w.x = pk2(fmaxf(bflo(raw[c4].x)*sc0.x+sh0.x,0.f), fmaxf(bfhi(raw[c4].x)*sc0.y+sh0.y,0.f));
      w.y = pk2(fmaxf(bflo(raw[c4].y)*sc0.z+sh0.z,0.f), fmaxf(bfhi(raw[c4].y)*sc0.w+sh0.w,0.f));
      w.z = pk2(fmaxf(bflo(raw[c4].z)*sc1.x+sh1.x,0.f), fmaxf(bfhi(raw[c4].z)*sc1.y+sh1.y,0.f));
      w.w = pk2(fmaxf(bflo(raw[c4].w)*sc1.z+sh1.z,0.f), fmaxf(bfhi(raw[c4].w)*sc1.w+sh1.w,0.f));
      *(uint4*)(As + (size_t)c*512 + (size_t)lane*8) = w;
    }
    #pragma unroll
    for(int c4=0;c4<2;c4++){
      int c = wave*2 + c4;
      int grow = c*8 + srow;            // 0..63
      const unsigned short* gb = Bt + (size_t)grow*K + k0 + sx;
      __builtin_amdgcn_global_load_lds((const __attribute__((address_space(1))) void*)gb,
          (__attribute__((address_space(3))) void*)(Bs + (size_t)c*512), 16, 0, 0);
    }
    __syncthreads();
    #pragma unroll
    for(int kk=0;kk<2;kk++){
      short8 af[2], bf[4];
      #pragma unroll
      for(int i=0;i<2;i++){
        int Ra = wm + i*16 + lrow;
        int ca = (kk*4 + lq) ^ (Ra & 7);
        af[i] = *(const short8*)(As + Ra*64 + ca*8);
      }
      #pragma unroll
      for(int j=0;j<4;j++){
        int Rb = j*16 + lrow;
        int cb = (kk*4 + lq) ^ (Rb & 7);
        bf[j] = *(const short8*)(Bs + Rb*64 + cb*8);
      }
      #pragma unroll
      for(int i=0;i<2;i++)
        #pragma unroll
        for(int j=0;j<4;j++)
          acc[i][j] = __builtin_amdgcn_mfma_f32_16x16x32_bf16(af[i], bf[j], acc[i][j], 0, 0, 0);
    }
  }
  #pragma unroll
  for(int j=0;j<4;j++){
    int col = j*16 + lrow;
    #pragma unroll
    for(int i=0;i<2;i++){
      #pragma unroll
      for(int r=0;r<4;r++){
        int row = m0 + wm + i*16 + lq*4 + r;
        if(row < M) X3p[(size_t)row*64 + col] = f2bf(acc[i][j][r] * rownorm[row]);
      }
    }
  }
}

// ---------------- launch ----------------

extern "C" void kernel_launch(void* const* d_in, const int* in_sizes, int n_in,
                              void* d_out, int out_size, void* d_ws, size_t ws_size,
                              hipStream_t stream){
  const float* x   = (const float*)d_in[0];
  const int*   src = (const int*)d_in[1];
  const int*   dst = (const int*)d_in[2];
  const float* W1  = (const float*)d_in[3];
  const float* b1  = (const float*)d_in[4];
  const float* g1  = (const float*)d_in[5];
  const float* be1 = (const float*)d_in[6];
  const float* W2  = (const float*)d_in[7];
  const float* b2  = (const float*)d_in[8];
  const float* g2  = (const float*)d_in[9];
  const float* be2 = (const float*)d_in[10];
  const float* W3  = (const float*)d_in[11];
  const float* b3  = (const float*)d_in[12];
  float* out = (float*)d_out;
  const int N = NN;
  const int E = in_sizes[1];

  char* p = (char*)d_ws;
  size_t off = 0;
  auto alloc = [&](size_t bytes)->void*{
    void* r = p + off;
    off += (bytes + 511) & ~(size_t)511;
    return r;
  };
  // Footprint ~184 MB — under the ~229 MB known-good high-water mark.
  int*   cnt   = (int*)  alloc((size_t)N*4);
  float* sums1 = (float*)alloc(2048);
  float* sums2 = (float*)alloc(2048);
  size_t zero_bytes = off;                       // cnt|sums zeroed each call
  int*   rp    = (int*)  alloc((size_t)(N+1)*4);
  float* norm  = (float*)alloc((size_t)(N+1)*4);
  float* scsh1 = (float*)alloc(2048);
  float* scsh2 = (float*)alloc(2048);
  int*   bfill = (int*)  alloc((size_t)NBUCK*16*4);                  // line-padded
  unsigned short* Wt1 = (unsigned short*)alloc((size_t)256*128*2);
  unsigned short* Wt2 = (unsigned short*)alloc((size_t)256*256*2);
  unsigned short* Wt3 = (unsigned short*)alloc((size_t)64*256*2);
  int*   esrc  = (int*)  alloc((size_t)(E + 7*N + 16)*4);            // pad-8 CSR
  unsigned short* Hx  = (unsigned short*)alloc((size_t)(N+1)*128*2); // x*norm + zero row
  unsigned short* M1  = (unsigned short*)alloc((size_t)N*128*2);     // agg128 out
  unsigned short* Mb2 = (unsigned short*)alloc((size_t)N*256*2);     // agg256 out
  unsigned short* Z   = (unsigned short*)alloc((size_t)(N+1)*256*2); // mgemm out + zero row
  unsigned short* X3p = (unsigned short*)alloc((size_t)(N+1)*64*2);  // layer-3 proj (64-col)
  // epairs (bucketed (src,dst) pairs, <=31.3MB) aliases Mb2 (51.2MB): dead
  // before k_agg256 writes Mb2 on this single stream.
  int2* epairs = (int2*)Mb2;
  // H2 = relu(bn(Z1))*norm, (N+1)x256 bf16 = 51,200,512 B. Aliases Hx(25,600,512)
  // + M1(25,600,000) — both dead after layer-1 mgemm; ends exactly at Mb2.
  unsigned short* H2 = Hx;
  (void)ws_size; (void)n_in; (void)out_size;

  hipMemsetAsync(d_ws, 0, zero_bytes, stream);

  k_hist   <<<(E+255)/256,256,0,stream>>>(dst, cnt, E);
  k_norm   <<<(N+256)/256,256,0,stream>>>(cnt, norm, N);
  k_scan   <<<1,1024,0,stream>>>(cnt, rp, N);
  k_binit  <<<(NBUCK+255)/256,256,0,stream>>>(rp, bfill);
  k_bucket1<<<(E+T1_TILE-1)/T1_TILE,256,0,stream>>>(src, dst, bfill, epairs, E);
  k_bucket2<<<NBUCK,256,0,stream>>>(epairs, bfill, rp, esrc);
  k_zeropad<<<1,256,0,stream>>>(Hx, X3p, Z);
  k_wprep  <<<(128*256+255)/256,256,0,stream>>>(W1, Wt1, 128, 256);
  k_wprep  <<<(256*256+255)/256,256,0,stream>>>(W2, Wt2, 256, 256);
  k_wprep3 <<<(64*256+255)/256,256,0,stream>>>(W3, Wt3);

  // layer 1: Hx = x*norm -> agg128*norm -> MFMA @W1+b1 (+stats) -> Z1(bf16)
  k_scale_x4<<<(N*32+255)/256,256,0,stream>>>(x, norm, Hx, N*32);
  k_agg128 <<<N,64,0,stream>>>(Hx, rp, esrc, norm, M1);
  k_mgemm  <<<((N+127)/128)*2,256,0,stream>>>(M1, Wt1, b1, Z, sums1, N, 128, 256);
  k_bnfin  <<<1,256,0,stream>>>(sums1, g1, be1, scsh1, N);

  // layer 2: H2 = relu(bn(Z1))*norm (one pass) -> plain agg256 -> MFMA @W2+b2 -> Z2
  k_bnrelu <<<((N+1)*32+255)/256,256,0,stream>>>(Z, scsh1, norm, H2, (N+1)*32);
  k_agg256 <<<N,64,0,stream>>>(H2, rp, esrc, norm, Mb2);
  k_mgemm  <<<((N+127)/128)*2,256,0,stream>>>(Mb2, Wt2, b2, Z, sums2, N, 256, 256);
  k_bnfin  <<<1,256,0,stream>>>(sums2, g2, be2, scsh2, N);

  // layer 3: mgemm3 applies BN+ReLU to Z2 in staging, X3p = (relu(bn(Z2))@W3p)*norm
  k_mgemm3 <<<(N+127)/128,256,0,stream>>>(Z, Wt3, scsh2, norm, X3p, N, 256);
  k_agg64  <<<N,64,0,stream>>>(X3p, rp, esrc, norm, b3, out);
}

// Round 3
// 817.389 us; speedup vs baseline: 1.5837x; 1.3476x over previous
//
#include <hip/hip_runtime.h>
#include <cstdint>
#include <cstddef>

#define NN 100000
#define BN_EPS 1e-5f

// bucketed CSR build: 128 nodes per bucket
#define NB_SHIFT 7
#define NBUCK ((NN >> NB_SHIFT) + 1)   // 782
#define BSLOT 6400                     // pair slots per bucket (mean 4093, sigma 64)
#define T1_EPT 16
#define T1_TILE (256*T1_EPT)           // 4096 edges per pass-1 block

typedef __attribute__((ext_vector_type(8))) short short8;
typedef __attribute__((ext_vector_type(4))) float f32x4;

static __device__ __forceinline__ float bflo(unsigned u){ return __uint_as_float(u<<16); }
static __device__ __forceinline__ float bfhi(unsigned u){ return __uint_as_float(u & 0xFFFF0000u); }
static __device__ __forceinline__ unsigned short f2bf(float f){
  unsigned u = __float_as_uint(f);
  u += 0x7FFFu + ((u>>16)&1u);   // round-to-nearest-even
  return (unsigned short)(u>>16);
}
static __device__ __forceinline__ unsigned pk2(float a, float b){
  return (unsigned)f2bf(a) | ((unsigned)f2bf(b) << 16);
}

// ---------------- graph prep (bucketed, histogram-free CSR build) ----------------

// pass 1: partition edges into NBUCK fixed-capacity segments of packed
// (src | localdst<<20) words. src < 2^17, localdst = dst&127 in bits 20..26.
// One global atomic per (block,bucket); bcnt line-padded (stride 16).
__global__ __launch_bounds__(256) void k_b1(const int* __restrict__ src,
    const int* __restrict__ dst, int* __restrict__ bcnt,
    int* __restrict__ epairs, int E){
  __shared__ int hist[NBUCK];
  int tid = threadIdx.x;
  for(int j=tid; j<NBUCK; j+=256) hist[j]=0;
  __syncthreads();
  int base = blockIdx.x*T1_TILE;
  int pk[T1_EPT], bk[T1_EPT], r[T1_EPT];
  #pragma unroll
  for(int i=0;i<T1_EPT;i++){
    int e = base + i*256 + tid;
    if(e<E){
      int s=src[e], d=dst[e];
      bk[i]=d>>NB_SHIFT;
      pk[i]= s | ((d&127)<<20);
      r[i]=atomicAdd(&hist[bk[i]], 1);
    }
  }
  __syncthreads();
  for(int j=tid; j<NBUCK; j+=256){
    int h = hist[j];
    if(h>0) hist[j] = atomicAdd(&bcnt[j*16], h);   // replace count with segment base
  }
  __syncthreads();
  #pragma unroll
  for(int i=0;i<T1_EPT;i++){
    int e = base + i*256 + tid;
    if(e<E) epairs[(size_t)bk[i]*BSLOT + hist[bk[i]] + r[i]] = pk[i];
  }
}

// pass 2a: per-bucket LDS degree histogram -> norm[] and padded bucket total.
__global__ __launch_bounds__(256) void k_b2a(const int* __restrict__ epairs,
    const int* __restrict__ bcnt, float* __restrict__ norm, int* __restrict__ ptot){
  __shared__ int h[128];
  int b = blockIdx.x, tid = threadIdx.x;
  if(tid<128) h[tid]=0;
  __syncthreads();
  int c = bcnt[b*16];
  const int* ep = epairs + (size_t)b*BSLOT;
  for(int j=tid; j<c; j+=256) atomicAdd(&h[ep[j]>>20], 1);
  __syncthreads();
  int n0 = b<<NB_SHIFT, nmax = min(128, NN-n0);
  if(tid<nmax) norm[n0+tid] = rsqrtf(fmaxf((float)h[tid], 1.0f));
  if(tid<64){
    int p0=(h[2*tid]+7)&~7, p1=(h[2*tid+1]+7)&~7;
    int s=p0+p1;
    #pragma unroll
    for(int off=1; off<64; off<<=1) s += __shfl_xor(s, off, 64);
    if(tid==0) ptot[b]=s;
  }
}

// scan over 782 bucket totals (tiny); also rp[NN] and norm[NN]=0.
__global__ __launch_bounds__(1024) void k_scanB(const int* __restrict__ ptot,
    int* __restrict__ bbase, int* __restrict__ rp, float* __restrict__ norm){
  __shared__ int sm[1024];
  int t = threadIdx.x;
  int v = (t<NBUCK)? ptot[t] : 0;
  sm[t]=v; __syncthreads();
  for(int off=1; off<1024; off<<=1){
    int u = (t>=off)? sm[t-off] : 0;
    __syncthreads();
    sm[t]+=u;
    __syncthreads();
  }
  if(t<NBUCK) bbase[t] = sm[t]-v;
  if(t==NBUCK-1){ bbase[NBUCK]=sm[t]; rp[NN]=sm[t]; }
  if(t==0) norm[NN]=0.f;
}

// pass 2b: re-hist, wave shuffle-scan of padded counts -> rp, place edges via
// LDS atomics, write pad slots (NN).
__global__ __launch_bounds__(256) void k_b2b(const int* __restrict__ epairs,
    const int* __restrict__ bcnt, const int* __restrict__ bbase,
    int* __restrict__ rp, int* __restrict__ esrc){
  __shared__ int h[128];
  __shared__ int loc[129];
  int b = blockIdx.x, tid = threadIdx.x;
  int n0 = b<<NB_SHIFT, nmax = min(128, NN-n0);
  if(tid<128) h[tid]=0;
  __syncthreads();
  int c = bcnt[b*16];
  const int* ep = epairs + (size_t)b*BSLOT;
  for(int j=tid; j<c; j+=256) atomicAdd(&h[ep[j]>>20], 1);
  __syncthreads();
  if(tid<64){
    int p0=(h[2*tid]+7)&~7, p1=(h[2*tid+1]+7)&~7;
    int s=p0+p1;
    #pragma unroll
    for(int off=1; off<64; off<<=1){ int u=__shfl_up(s, off, 64); if(tid>=off) s+=u; }
    loc[2*tid]   = s-p0-p1;
    loc[2*tid+1] = s-p1;
    if(tid==63) loc[128]=s;
  }
  __syncthreads();
  int base = bbase[b];
  if(tid<nmax) rp[n0+tid] = base + loc[tid];
  if(tid<128) h[tid] = base + loc[tid];          // becomes fill pointer
  __syncthreads();
  for(int j=tid; j<c; j+=256){
    int p = ep[j];
    int pos = atomicAdd(&h[p>>20], 1);
    esrc[pos] = p & 0xFFFFF;
  }
  __syncthreads();
  for(int i=tid; i<nmax; i+=256){
    int end = base + loc[i+1];
    for(int j=h[i]; j<end; j++) esrc[j]=NN;
  }
}

// zero pad rows: Hx row NN (128), X3p row NN (40), Z row NN (256)
__global__ void k_zeropad(unsigned short* __restrict__ Hx, unsigned short* __restrict__ X3p,
                          unsigned short* __restrict__ Z){
  int t = threadIdx.x;
  if(t<128) Hx[(size_t)NN*128 + t] = 0;
  if(t<40)  X3p[(size_t)NN*40 + t] = 0;
  Z[(size_t)NN*256 + t] = 0;
}

// ---------------- elementwise / weight prep ----------------

// x*norm -> bf16, float4/lane (4 elems), 32 float4 per 128-col row
__global__ void k_scale_x4(const float* __restrict__ x, const float* __restrict__ norm,
                           unsigned short* __restrict__ H, int total4){
  int i = blockIdx.x*blockDim.x + threadIdx.x;
  if(i<total4){
    float4 v = *(const float4*)(x + (size_t)i*4);
    float nn = norm[i>>5];
    uint2 w;
    w.x = pk2(v.x*nn, v.y*nn);
    w.y = pk2(v.z*nn, v.w*nn);
    *(uint2*)(H + (size_t)i*4) = w;
  }
}

// H2 = relu(bn(Z1)) * norm[row], bf16, over N+1 rows (row NN -> 0 via norm=0).
__global__ void k_bnrelu(const unsigned short* __restrict__ Z, const float* __restrict__ scsh,
                         const float* __restrict__ norm, unsigned short* __restrict__ H2,
                         int total4){
  int i = blockIdx.x*blockDim.x + threadIdx.x;
  if(i<total4){
    int c8 = (i & 31) * 8;
    float nn = norm[i>>5];
    uint4 v = *(const uint4*)(Z + (size_t)i*8);
    float4 sc0 = *(const float4*)(scsh + c8);
    float4 sc1 = *(const float4*)(scsh + c8 + 4);
    float4 sh0 = *(const float4*)(scsh + 256 + c8);
    float4 sh1 = *(const float4*)(scsh + 256 + c8 + 4);
    uint4 w;
    w.x = pk2(fmaxf(bflo(v.x)*sc0.x+sh0.x,0.f)*nn, fmaxf(bfhi(v.x)*sc0.y+sh0.y,0.f)*nn);
    w.y = pk2(fmaxf(bflo(v.y)*sc0.z+sh0.z,0.f)*nn, fmaxf(bfhi(v.y)*sc0.w+sh0.w,0.f)*nn);
    w.z = pk2(fmaxf(bflo(v.z)*sc1.x+sh1.x,0.f)*nn, fmaxf(bfhi(v.z)*sc1.y+sh1.y,0.f)*nn);
    w.w = pk2(fmaxf(bflo(v.w)*sc1.z+sh1.z,0.f)*nn, fmaxf(bfhi(v.w)*sc1.w+sh1.w,0.f)*nn);
    *(uint4*)(H2 + (size_t)i*8) = w;
  }
}

// W (K x N fp32) -> Wt (N x K bf16)
__global__ void k_wprep(const float* __restrict__ W, unsigned short* __restrict__ Wt, int K, int N){
  int i = blockIdx.x*blockDim.x + threadIdx.x;
  if(i < K*N){
    int k = i / N, n = i - k*N;
    Wt[(size_t)n*K + k] = f2bf(W[i]);
  }
}

// W3 (256 x 40 fp32) -> Wt3 (64 x 256 bf16), rows >= 40 zero
__global__ void k_wprep3(const float* __restrict__ W3, unsigned short* __restrict__ Wt){
  int i = blockIdx.x*blockDim.x + threadIdx.x;
  if(i < 64*256){
    int n = i >> 8, k = i & 255;
    Wt[i] = (n < 40) ? f2bf(W3[(size_t)k*40 + n]) : (unsigned short)0;
  }
}

// ---------------- BN finalize ----------------

__global__ void k_bnfin(const float* __restrict__ sums, const float* __restrict__ gamma,
                        const float* __restrict__ beta, float* __restrict__ scsh, int M){
  int c = threadIdx.x;
  float mean = sums[c]/(float)M;
  float var  = sums[256+c]/(float)M - mean*mean;
  float sc = gamma[c]*rsqrtf(var + BN_EPS);
  scsh[c] = sc;
  scsh[256+c] = beta[c] - mean*sc;
}

// ---------------- aggregation (wave per node, padded CSR, pure sum) ----------------

// 128-col rows (256B): 4 edge-groups x 16 lanes x uint4(16B). 8 edges/iter.
__global__ __launch_bounds__(64) void k_agg128(const unsigned short* __restrict__ H,
    const int* __restrict__ rp, const int* __restrict__ esrc,
    const float* __restrict__ norm, unsigned short* __restrict__ out){
  int node = blockIdx.x, lane = threadIdx.x;
  int s0 = rp[node], s1 = rp[node+1];
  int g = lane >> 4, c = lane & 15;
  float a[8] = {};
  for(int e=s0; e<s1; e+=8){
    int4 A4 = *(const int4*)(esrc+e);
    int4 B4 = *(const int4*)(esrc+e+4);
    int i0 = g==0?A4.x: g==1?A4.y: g==2?A4.z: A4.w;
    int i1 = g==0?B4.x: g==1?B4.y: g==2?B4.z: B4.w;
    uint4 v0 = *(const uint4*)(H + (size_t)i0*128 + c*8);
    uint4 v1 = *(const uint4*)(H + (size_t)i1*128 + c*8);
    a[0]+=bflo(v0.x)+bflo(v1.x); a[1]+=bfhi(v0.x)+bfhi(v1.x);
    a[2]+=bflo(v0.y)+bflo(v1.y); a[3]+=bfhi(v0.y)+bfhi(v1.y);
    a[4]+=bflo(v0.z)+bflo(v1.z); a[5]+=bfhi(v0.z)+bfhi(v1.z);
    a[6]+=bflo(v0.w)+bflo(v1.w); a[7]+=bfhi(v0.w)+bfhi(v1.w);
  }
  #pragma unroll
  for(int j=0;j<8;j++){
    a[j] += __shfl_xor(a[j], 16, 64);
    a[j] += __shfl_xor(a[j], 32, 64);
  }
  if(g==0){
    float nn = norm[node];
    uint4 w;
    w.x = pk2(a[0]*nn, a[1]*nn);
    w.y = pk2(a[2]*nn, a[3]*nn);
    w.z = pk2(a[4]*nn, a[5]*nn);
    w.w = pk2(a[6]*nn, a[7]*nn);
    *(uint4*)(out + (size_t)node*128 + c*8) = w;
  }
}

// 256-col rows (512B): 2 edge-groups x 32 lanes x uint4(16B). 8 edges/iter.
__global__ __launch_bounds__(64) void k_agg256(const unsigned short* __restrict__ H,
    const int* __restrict__ rp, const int* __restrict__ esrc,
    const float* __restrict__ norm, unsigned short* __restrict__ out){
  int node = blockIdx.x, lane = threadIdx.x;
  int s0 = rp[node], s1 = rp[node+1];
  int g = lane >> 5, c = lane & 31;
  float a[8] = {};
  for(int e=s0; e<s1; e+=8){
    int4 A4 = *(const int4*)(esrc+e);
    int4 B4 = *(const int4*)(esrc+e+4);
    int i0 = g ? A4.y : A4.x;
    int i1 = g ? A4.w : A4.z;
    int i2 = g ? B4.y : B4.x;
    int i3 = g ? B4.w : B4.z;
    uint4 v0 = *(const uint4*)(H + (size_t)i0*256 + c*8);
    uint4 v1 = *(const uint4*)(H + (size_t)i1*256 + c*8);
    uint4 v2 = *(const uint4*)(H + (size_t)i2*256 + c*8);
    uint4 v3 = *(const uint4*)(H + (size_t)i3*256 + c*8);
    a[0]+=bflo(v0.x)+bflo(v1.x)+bflo(v2.x)+bflo(v3.x);
    a[1]+=bfhi(v0.x)+bfhi(v1.x)+bfhi(v2.x)+bfhi(v3.x);
    a[2]+=bflo(v0.y)+bflo(v1.y)+bflo(v2.y)+bflo(v3.y);
    a[3]+=bfhi(v0.y)+bfhi(v1.y)+bfhi(v2.y)+bfhi(v3.y);
    a[4]+=bflo(v0.z)+bflo(v1.z)+bflo(v2.z)+bflo(v3.z);
    a[5]+=bfhi(v0.z)+bfhi(v1.z)+bfhi(v2.z)+bfhi(v3.z);
    a[6]+=bflo(v0.w)+bflo(v1.w)+bflo(v2.w)+bflo(v3.w);
    a[7]+=bfhi(v0.w)+bfhi(v1.w)+bfhi(v2.w)+bfhi(v3.w);
  }
  #pragma unroll
  for(int j=0;j<8;j++) a[j] += __shfl_xor(a[j], 32, 64);
  if(g==0){
    float nn = norm[node];
    uint4 w;
    w.x = pk2(a[0]*nn, a[1]*nn);
    w.y = pk2(a[2]*nn, a[3]*nn);
    w.z = pk2(a[4]*nn, a[5]*nn);
    w.w = pk2(a[6]*nn, a[7]*nn);
    *(uint4*)(out + (size_t)node*256 + c*8) = w;
  }
}

// final aggregation: X3p rows 40 bf16 (80B, 16B-aligned since 80=5*16).
// 8 edge-groups x 8 lanes; lanes s<5 load uint4, s>=5 idle (saves 37% bytes).
__global__ __launch_bounds__(64) void k_agg64(const unsigned short* __restrict__ X3p,
    const int* __restrict__ rp, const int* __restrict__ esrc,
    const float* __restrict__ norm, const float* __restrict__ b3,
    float* __restrict__ out){
  int node = blockIdx.x, lane = threadIdx.x;
  int s0 = rp[node], s1 = rp[node+1];
  int es = lane >> 3, s = lane & 7;
  float a[8] = {};
  for(int e=s0; e<s1; e+=8){
    int4 A4 = *(const int4*)(esrc+e);
    int4 B4 = *(const int4*)(esrc+e+4);
    int idx = es==0?A4.x: es==1?A4.y: es==2?A4.z: es==3?A4.w:
              es==4?B4.x: es==5?B4.y: es==6?B4.z: B4.w;
    if(s<5){
      uint4 v = *(const uint4*)(X3p + (size_t)idx*40 + s*8);
      a[0]+=bflo(v.x); a[1]+=bfhi(v.x); a[2]+=bflo(v.y); a[3]+=bfhi(v.y);
      a[4]+=bflo(v.z); a[5]+=bfhi(v.z); a[6]+=bflo(v.w); a[7]+=bfhi(v.w);
    }
  }
  #pragma unroll
  for(int off=8; off<64; off<<=1){
    #pragma unroll
    for(int j=0;j<8;j++) a[j] += __shfl_xor(a[j], off, 64);
  }
  bool act = s < 5;   // cols s*8..s*8+7 < 40
  float nn = norm[node];
  float bv[8] = {};
  if(act){
    float4 t0 = *(const float4*)(b3 + s*8);
    float4 t1 = *(const float4*)(b3 + s*8 + 4);
    bv[0]=t0.x; bv[1]=t0.y; bv[2]=t0.z; bv[3]=t0.w;
    bv[4]=t1.x; bv[5]=t1.y; bv[6]=t1.z; bv[7]=t1.w;
  }
  float v[8];
  float mx = -INFINITY;
  #pragma unroll
  for(int j=0;j<8;j++){
    v[j] = act ? (a[j]*nn + bv[j]) : -INFINITY;
    mx = fmaxf(mx, v[j]);
  }
  #pragma unroll
  for(int off=32; off; off>>=1) mx = fmaxf(mx, __shfl_xor(mx, off, 64));
  float sum = 0.f;
  if(act && es==0){
    #pragma unroll
    for(int j=0;j<8;j++) sum += expf(v[j]-mx);
  }
  #pragma unroll
  for(int off=32; off; off>>=1) sum += __shfl_xor(sum, off, 64);
  float lse = logf(sum);
  if(act && es==0){
    float4 o0, o1;
    o0.x=v[0]-mx-lse; o0.y=v[1]-mx-lse; o0.z=v[2]-mx-lse; o0.w=v[3]-mx-lse;
    o1.x=v[4]-mx-lse; o1.y=v[5]-mx-lse; o1.z=v[6]-mx-lse; o1.w=v[7]-mx-lse;
    *(float4*)(out + (size_t)node*40 + s*8) = o0;
    *(float4*)(out + (size_t)node*40 + s*8 + 4) = o1;
  }
}

// ---------------- MFMA GEMM: C = A*Bt^T + bias (bf16 out) + fused column stats ----------------

__global__ __launch_bounds__(256) void k_mgemm(
    const unsigned short* __restrict__ A, const unsigned short* __restrict__ Bt,
    const float* __restrict__ bias, unsigned short* __restrict__ C,
    float* __restrict__ sums, int M, int K, int Nn){
  __shared__ unsigned short As[128*64];
  __shared__ unsigned short Bs[128*64];
  int nt = Nn >> 7;
  int bm = blockIdx.x / nt, bn = blockIdx.x % nt;
  int m0 = bm*128, n0 = bn*128;
  int tid = threadIdx.x;
  int wave = tid >> 6, lane = tid & 63;
  int wm = (wave>>1)*64, wn = (wave&1)*64;
  int lrow = lane & 15, lq = lane >> 4;
  int srow = lane >> 3;
  int sx = ((lane & 7) ^ srow) * 8;
  f32x4 acc[4][4] = {};
  for(int k0=0; k0<K; k0+=64){
    __syncthreads();
    #pragma unroll
    for(int c4=0;c4<4;c4++){
      int c = wave*4 + c4;
      int grow = c*8 + srow;
      const unsigned short* ga = A + (size_t)(m0+grow)*K + k0 + sx;
      __builtin_amdgcn_global_load_lds((const __attribute__((address_space(1))) void*)ga,
          (__attribute__((address_space(3))) void*)(As + (size_t)c*512), 16, 0, 0);
      const unsigned short* gb = Bt + (size_t)(n0+grow)*K + k0 + sx;
      __builtin_amdgcn_global_load_lds((const __attribute__((address_space(1))) void*)gb,
          (__attribute__((address_space(3))) void*)(Bs + (size_t)c*512), 16, 0, 0);
    }
    __syncthreads();
    #pragma unroll
    for(int kk=0;kk<2;kk++){
      short8 af[4], bf[4];
      #pragma unroll
      for(int i=0;i<4;i++){
        int Ra = wm + i*16 + lrow;
        int ca = (kk*4 + lq) ^ (Ra & 7);
        af[i] = *(const short8*)(As + Ra*64 + ca*8);
        int Rb = wn + i*16 + lrow;
        int cb = (kk*4 + lq) ^ (Rb & 7);
        bf[i] = *(const short8*)(Bs + Rb*64 + cb*8);
      }
      #pragma unroll
      for(int i=0;i<4;i++)
        #pragma unroll
        for(int j=0;j<4;j++)
          acc[i][j] = __builtin_amdgcn_mfma_f32_16x16x32_bf16(af[i], bf[j], acc[i][j], 0, 0, 0);
    }
  }
  // epilogue: write C (bf16) and accumulate column sum/sumsq for BN stats
  #pragma unroll
  for(int j=0;j<4;j++){
    int col = n0 + wn + j*16 + lrow;
    float bj = bias[col];
    float s=0.f, s2=0.f;
    #pragma unroll
    for(int i=0;i<4;i++){
      #pragma unroll
      for(int r=0;r<4;r++){
        int row = m0 + wm + i*16 + lq*4 + r;
        if(row < M){
          float v = acc[i][j][r] + bj;
          s += v; s2 += v*v;
          C[(size_t)row*Nn + col] = f2bf(v);
        }
      }
    }
    s  += __shfl_xor(s, 16, 64);  s  += __shfl_xor(s, 32, 64);
    s2 += __shfl_xor(s2, 16, 64); s2 += __shfl_xor(s2, 32, 64);
    if(lq == 0){
      atomicAdd(&sums[col], s);
      atomicAdd(&sums[256+col], s2);
    }
  }
}

// layer-3: 128x64 tile; A-staging applies BN+ReLU (scsh) on the fly (reg->LDS);
// out X3p bf16 stride 40 (*rownorm), cols>=40 discarded. Bt = Wt3 (64 x K).
__global__ __launch_bounds__(256) void k_mgemm3(
    const unsigned short* __restrict__ Zin, const unsigned short* __restrict__ Bt,
    const float* __restrict__ scsh, const float* __restrict__ rownorm,
    unsigned short* __restrict__ X3p, int M, int K){
  __shared__ unsigned short As[128*64];
  __shared__ unsigned short Bs[64*64];
  int m0 = blockIdx.x*128;
  int tid = threadIdx.x;
  int wave = tid >> 6, lane = tid & 63;
  int wm = wave*32;
  int lrow = lane & 15, lq = lane >> 4;
  int srow = lane >> 3;
  int sx = ((lane & 7) ^ srow) * 8;
  f32x4 acc[2][4] = {};
  for(int k0=0; k0<K; k0+=64){
    // prefetch raw A (pre-BN Z2) to regs while previous iter computes
    uint4 raw[4];
    #pragma unroll
    for(int c4=0;c4<4;c4++){
      int c = wave*4 + c4;
      int grow = c*8 + srow;
      raw[c4] = *(const uint4*)(Zin + (size_t)(m0+grow)*K + k0 + sx);
    }
    float4 sc0 = *(const float4*)(scsh + k0 + sx);
    float4 sc1 = *(const float4*)(scsh + k0 + sx + 4);
    float4 sh0 = *(const float4*)(scsh + 256 + k0 + sx);
    float4 sh1 = *(const float4*)(scsh + 256 + k0 + sx + 4);
    __syncthreads();                 // previous iter's LDS reads done
    #pragma unroll
    for(int c4=0;c4<4;c4++){
      int c = wave*4 + c4;
      uint4 w;
      w.x = pk2(fmaxf(bflo(raw[c4].x)*sc0.x+sh0.x,0.f), fmaxf(bfhi(raw[c4].x)*sc0.y+sh0.y,0.f));
      w.y = pk2(fmaxf(bflo(raw[c4].y)*sc0.z+sh0.z,0.f), fmaxf(bfhi(raw[c4].y)*sc0.w+sh0.w,0.f));
      w.z = pk2(fmaxf(bflo(raw[c4].z)*sc1.x+sh1.x,0.f), fmaxf(bfhi(raw[c4].z)*sc1.y+sh1.y,0.f));
      w.w = pk2(fmaxf(bflo(raw[c4].w)*sc1.z+sh1.z,0.f), fmaxf(bfhi(raw[c4].w)*sc1.w+sh1.w,0.f));
      *(uint4*)(As + (size_t)c*512 + (size_t)lane*8) = w;
    }
    #pragma unroll
    for(int c4=0;c4<2;c4++){
      int c = wave*2 + c4;
      int grow = c*8 + srow;            // 0..63
      const unsigned short* gb = Bt + (size_t)grow*K + k0 + sx;
      __builtin_amdgcn_global_load_lds((const __attribute__((address_space(1))) void*)gb,
          (__attribute__((address_space(3))) void*)(Bs + (size_t)c*512), 16, 0, 0);
    }
    __syncthreads();
    #pragma unroll
    for(int kk=0;kk<2;kk++){
      short8 af[2], bf[4];
      #pragma unroll
      for(int i=0;i<2;i++){
        int Ra = wm + i*16 + lrow;
        int ca = (kk*4 + lq) ^ (Ra & 7);
        af[i] = *(const short8*)(As + Ra*64 + ca*8);
      }
      #pragma unroll
      for(int j=0;j<4;j++){
        int Rb = j*16 + lrow;
        int cb = (kk*4 + lq) ^ (Rb & 7);
        bf[j] = *(const short8*)(Bs + Rb*64 + cb*8);
      }
      #pragma unroll
      for(int i=0;i<2;i++)
        #pragma unroll
        for(int j=0;j<4;j++)
          acc[i][j] = __builtin_amdgcn_mfma_f32_16x16x32_bf16(af[i], bf[j], acc[i][j], 0, 0, 0);
    }
  }
  #pragma unroll
  for(int j=0;j<4;j++){
    int col = j*16 + lrow;
    if(col < 40){
      #pragma unroll
      for(int i=0;i<2;i++){
        #pragma unroll
        for(int r=0;r<4;r++){
          int row = m0 + wm + i*16 + lq*4 + r;
          if(row < M) X3p[(size_t)row*40 + col] = f2bf(acc[i][j][r] * rownorm[row]);
        }
      }
    }
  }
}

// ---------------- launch ----------------

extern "C" void kernel_launch(void* const* d_in, const int* in_sizes, int n_in,
                              void* d_out, int out_size, void* d_ws, size_t ws_size,
                              hipStream_t stream){
  const float* x   = (const float*)d_in[0];
  const int*   src = (const int*)d_in[1];
  const int*   dst = (const int*)d_in[2];
  const float* W1  = (const float*)d_in[3];
  const float* b1  = (const float*)d_in[4];
  const float* g1  = (const float*)d_in[5];
  const float* be1 = (const float*)d_in[6];
  const float* W2  = (const float*)d_in[7];
  const float* b2  = (const float*)d_in[8];
  const float* g2  = (const float*)d_in[9];
  const float* be2 = (const float*)d_in[10];
  const float* W3  = (const float*)d_in[11];
  const float* b3  = (const float*)d_in[12];
  float* out = (float*)d_out;
  const int N = NN;
  const int E = in_sizes[1];

  char* p = (char*)d_ws;
  size_t off = 0;
  auto alloc = [&](size_t bytes)->void*{
    void* r = p + off;
    off += (bytes + 511) & ~(size_t)511;
    return r;
  };
  // Footprint ~168 MB — under the ~229 MB known-good high-water mark.
  int*   bcnt  = (int*)  alloc((size_t)NBUCK*16*4);  // line-padded bucket counters
  float* sums1 = (float*)alloc(2048);
  float* sums2 = (float*)alloc(2048);
  size_t zero_bytes = off;                           // bcnt|sums zeroed each call
  int*   rp    = (int*)  alloc((size_t)(N+1)*4);
  float* norm  = (float*)alloc((size_t)(N+1)*4);
  float* scsh1 = (float*)alloc(2048);
  float* scsh2 = (float*)alloc(2048);
  int*   ptot  = (int*)  alloc((size_t)NBUCK*4);
  int*   bbase = (int*)  alloc((size_t)(NBUCK+1)*4);
  unsigned short* Wt1 = (unsigned short*)alloc((size_t)256*128*2);
  unsigned short* Wt2 = (unsigned short*)alloc((size_t)256*256*2);
  unsigned short* Wt3 = (unsigned short*)alloc((size_t)64*256*2);
  int*   esrc  = (int*)  alloc((size_t)(E + 7*N + 16)*4);            // pad-8 CSR
  unsigned short* Hx  = (unsigned short*)alloc((size_t)(N+1)*128*2); // x*norm + zero row
  unsigned short* M1  = (unsigned short*)alloc((size_t)N*128*2);     // agg128 out
  unsigned short* Mb2 = (unsigned short*)alloc((size_t)N*256*2);     // agg256 out
  unsigned short* Z   = (unsigned short*)alloc((size_t)(N+1)*256*2); // mgemm out + zero row
  unsigned short* X3p = (unsigned short*)alloc((size_t)(N+1)*40*2);  // layer-3 proj (40-col)
  // epairs (packed bucket words, 782*6400*4 = 20MB) aliases Mb2 (51.2MB):
  // dead before k_agg256 writes Mb2 on this single stream.
  int* epairs = (int*)Mb2;
  // H2 = relu(bn(Z1))*norm, (N+1)x256 bf16 = 51,200,512 B. Aliases Hx(25,600,512)
  // + M1(25,600,000) — both dead after layer-1 mgemm; ends exactly at Mb2.
  unsigned short* H2 = Hx;
  (void)ws_size; (void)n_in; (void)out_size;

  hipMemsetAsync(d_ws, 0, zero_bytes, stream);

  k_b1    <<<(E+T1_TILE-1)/T1_TILE,256,0,stream>>>(src, dst, bcnt, epairs, E);
  k_b2a   <<<NBUCK,256,0,stream>>>(epairs, bcnt, norm, ptot);
  k_scanB <<<1,1024,0,stream>>>(ptot, bbase, rp, norm);
  k_b2b   <<<NBUCK,256,0,stream>>>(epairs, bcnt, bbase, rp, esrc);
  k_zeropad<<<1,256,0,stream>>>(Hx, X3p, Z);
  k_wprep  <<<(128*256+255)/256,256,0,stream>>>(W1, Wt1, 128, 256);
  k_wprep  <<<(256*256+255)/256,256,0,stream>>>(W2, Wt2, 256, 256);
  k_wprep3 <<<(64*256+255)/256,256,0,stream>>>(W3, Wt3);

  // layer 1: Hx = x*norm -> agg128*norm -> MFMA @W1+b1 (+stats) -> Z1(bf16)
  k_scale_x4<<<(N*32+255)/256,256,0,stream>>>(x, norm, Hx, N*32);
  k_agg128 <<<N,64,0,stream>>>(Hx, rp, esrc, norm, M1);
  k_mgemm  <<<((N+127)/128)*2,256,0,stream>>>(M1, Wt1, b1, Z, sums1, N, 128, 256);
  k_bnfin  <<<1,256,0,stream>>>(sums1, g1, be1, scsh1, N);

  // layer 2: H2 = relu(bn(Z1))*norm (one pass) -> plain agg256 -> MFMA @W2+b2 -> Z2
  k_bnrelu <<<((N+1)*32+255)/256,256,0,stream>>>(Z, scsh1, norm, H2, (N+1)*32);
  k_agg256 <<<N,64,0,stream>>>(H2, rp, esrc, norm, Mb2);
  k_mgemm  <<<((N+127)/128)*2,256,0,stream>>>(Mb2, Wt2, b2, Z, sums2, N, 256, 256);
  k_bnfin  <<<1,256,0,stream>>>(sums2, g2, be2, scsh2, N);

  // layer 3: mgemm3 applies BN+ReLU to Z2 in staging, X3p = (relu(bn(Z2))@W3p)*norm
  k_mgemm3 <<<(N+127)/128,256,0,stream>>>(Z, Wt3, scsh2, norm, X3p, N, 256);
  k_agg64  <<<N,64,0,stream>>>(X3p, rp, esrc, norm, b3, out);
}

// Round 4
// 799.246 us; speedup vs baseline: 1.6197x; 1.0227x over previous
//
#include <hip/hip_runtime.h>
#include <cstdint>
#include <cstddef>

#define NN 100000
#define BN_EPS 1e-5f

// bucketed CSR build: 128 nodes per bucket
#define NB_SHIFT 7
#define NBUCK ((NN >> NB_SHIFT) + 1)   // 782
#define BSLOT 6400                     // pair slots per bucket (mean 4093, sigma 64)
#define T1_EPT 16
#define T1_TILE (256*T1_EPT)           // 4096 edges per pass-1 block

typedef __attribute__((ext_vector_type(8))) short short8;
typedef __attribute__((ext_vector_type(4))) float f32x4;

static __device__ __forceinline__ float bflo(unsigned u){ return __uint_as_float(u<<16); }
static __device__ __forceinline__ float bfhi(unsigned u){ return __uint_as_float(u & 0xFFFF0000u); }
static __device__ __forceinline__ unsigned short f2bf(float f){
  unsigned u = __float_as_uint(f);
  u += 0x7FFFu + ((u>>16)&1u);   // round-to-nearest-even
  return (unsigned short)(u>>16);
}
static __device__ __forceinline__ unsigned pk2(float a, float b){
  return (unsigned)f2bf(a) | ((unsigned)f2bf(b) << 16);
}

// ---------------- graph prep (bucketed, histogram-free CSR build) ----------------

// pass 1: partition edges into NBUCK fixed-capacity segments of packed
// (src | localdst<<20) words. src < 2^17, localdst = dst&127 in bits 20..26.
__global__ __launch_bounds__(256) void k_b1(const int* __restrict__ src,
    const int* __restrict__ dst, int* __restrict__ bcnt,
    int* __restrict__ epairs, int E){
  __shared__ int hist[NBUCK];
  int tid = threadIdx.x;
  for(int j=tid; j<NBUCK; j+=256) hist[j]=0;
  __syncthreads();
  int base = blockIdx.x*T1_TILE;
  int pk[T1_EPT], bk[T1_EPT], r[T1_EPT];
  #pragma unroll
  for(int i=0;i<T1_EPT;i++){
    int e = base + i*256 + tid;
    if(e<E){
      int s=src[e], d=dst[e];
      bk[i]=d>>NB_SHIFT;
      pk[i]= s | ((d&127)<<20);
      r[i]=atomicAdd(&hist[bk[i]], 1);
    }
  }
  __syncthreads();
  for(int j=tid; j<NBUCK; j+=256){
    int h = hist[j];
    if(h>0) hist[j] = atomicAdd(&bcnt[j*16], h);   // replace count with segment base
  }
  __syncthreads();
  #pragma unroll
  for(int i=0;i<T1_EPT;i++){
    int e = base + i*256 + tid;
    if(e<E) epairs[(size_t)bk[i]*BSLOT + hist[bk[i]] + r[i]] = pk[i];
  }
}

// pass 2a: per-bucket LDS degree histogram -> norm[] and padded bucket total.
__global__ __launch_bounds__(256) void k_b2a(const int* __restrict__ epairs,
    const int* __restrict__ bcnt, float* __restrict__ norm, int* __restrict__ ptot){
  __shared__ int h[128];
  int b = blockIdx.x, tid = threadIdx.x;
  if(tid<128) h[tid]=0;
  __syncthreads();
  int c = bcnt[b*16];
  const int* ep = epairs + (size_t)b*BSLOT;
  for(int j=tid; j<c; j+=256) atomicAdd(&h[ep[j]>>20], 1);
  __syncthreads();
  int n0 = b<<NB_SHIFT, nmax = min(128, NN-n0);
  if(tid<nmax) norm[n0+tid] = rsqrtf(fmaxf((float)h[tid], 1.0f));
  if(tid<64){
    int p0=(h[2*tid]+7)&~7, p1=(h[2*tid+1]+7)&~7;
    int s=p0+p1;
    #pragma unroll
    for(int off=1; off<64; off<<=1) s += __shfl_xor(s, off, 64);
    if(tid==0) ptot[b]=s;
  }
}

// scan over 782 bucket totals (tiny); also rp[NN] and norm[NN]=0.
__global__ __launch_bounds__(1024) void k_scanB(const int* __restrict__ ptot,
    int* __restrict__ bbase, int* __restrict__ rp, float* __restrict__ norm){
  __shared__ int sm[1024];
  int t = threadIdx.x;
  int v = (t<NBUCK)? ptot[t] : 0;
  sm[t]=v; __syncthreads();
  for(int off=1; off<1024; off<<=1){
    int u = (t>=off)? sm[t-off] : 0;
    __syncthreads();
    sm[t]+=u;
    __syncthreads();
  }
  if(t<NBUCK) bbase[t] = sm[t]-v;
  if(t==NBUCK-1){ bbase[NBUCK]=sm[t]; rp[NN]=sm[t]; }
  if(t==0) norm[NN]=0.f;
}

// pass 2b: re-hist, wave shuffle-scan of padded counts -> rp, place edges via
// LDS atomics, write pad slots (NN).
__global__ __launch_bounds__(256) void k_b2b(const int* __restrict__ epairs,
    const int* __restrict__ bcnt, const int* __restrict__ bbase,
    int* __restrict__ rp, int* __restrict__ esrc){
  __shared__ int h[128];
  __shared__ int loc[129];
  int b = blockIdx.x, tid = threadIdx.x;
  int n0 = b<<NB_SHIFT, nmax = min(128, NN-n0);
  if(tid<128) h[tid]=0;
  __syncthreads();
  int c = bcnt[b*16];
  const int* ep = epairs + (size_t)b*BSLOT;
  for(int j=tid; j<c; j+=256) atomicAdd(&h[ep[j]>>20], 1);
  __syncthreads();
  if(tid<64){
    int p0=(h[2*tid]+7)&~7, p1=(h[2*tid+1]+7)&~7;
    int s=p0+p1;
    #pragma unroll
    for(int off=1; off<64; off<<=1){ int u=__shfl_up(s, off, 64); if(tid>=off) s+=u; }
    loc[2*tid]   = s-p0-p1;
    loc[2*tid+1] = s-p1;
    if(tid==63) loc[128]=s;
  }
  __syncthreads();
  int base = bbase[b];
  if(tid<nmax) rp[n0+tid] = base + loc[tid];
  if(tid<128) h[tid] = base + loc[tid];          // becomes fill pointer
  __syncthreads();
  for(int j=tid; j<c; j+=256){
    int p = ep[j];
    int pos = atomicAdd(&h[p>>20], 1);
    esrc[pos] = p & 0xFFFFF;
  }
  __syncthreads();
  for(int i=tid; i<nmax; i+=256){
    int end = base + loc[i+1];
    for(int j=h[i]; j<end; j++) esrc[j]=NN;
  }
}

// zero pad rows: Hx row NN (128), X3p row NN (40), Z row NN (256)
__global__ void k_zeropad(unsigned short* __restrict__ Hx, unsigned short* __restrict__ X3p,
                          unsigned short* __restrict__ Z){
  int t = threadIdx.x;
  if(t<128) Hx[(size_t)NN*128 + t] = 0;
  if(t<40)  X3p[(size_t)NN*40 + t] = 0;
  Z[(size_t)NN*256 + t] = 0;
}

// ---------------- elementwise / weight prep ----------------

// x*norm -> bf16, float4/lane (4 elems), 32 float4 per 128-col row
__global__ void k_scale_x4(const float* __restrict__ x, const float* __restrict__ norm,
                           unsigned short* __restrict__ H, int total4){
  int i = blockIdx.x*blockDim.x + threadIdx.x;
  if(i<total4){
    float4 v = *(const float4*)(x + (size_t)i*4);
    float nn = norm[i>>5];
    uint2 w;
    w.x = pk2(v.x*nn, v.y*nn);
    w.y = pk2(v.z*nn, v.w*nn);
    *(uint2*)(H + (size_t)i*4) = w;
  }
}

// H2 = relu(bn(Z1)) * norm[row], bf16, over N+1 rows (row NN -> 0 via norm=0).
__global__ void k_bnrelu(const unsigned short* __restrict__ Z, const float* __restrict__ scsh,
                         const float* __restrict__ norm, unsigned short* __restrict__ H2,
                         int total4){
  int i = blockIdx.x*blockDim.x + threadIdx.x;
  if(i<total4){
    int c8 = (i & 31) * 8;
    float nn = norm[i>>5];
    uint4 v = *(const uint4*)(Z + (size_t)i*8);
    float4 sc0 = *(const float4*)(scsh + c8);
    float4 sc1 = *(const float4*)(scsh + c8 + 4);
    float4 sh0 = *(const float4*)(scsh + 256 + c8);
    float4 sh1 = *(const float4*)(scsh + 256 + c8 + 4);
    uint4 w;
    w.x = pk2(fmaxf(bflo(v.x)*sc0.x+sh0.x,0.f)*nn, fmaxf(bfhi(v.x)*sc0.y+sh0.y,0.f)*nn);
    w.y = pk2(fmaxf(bflo(v.y)*sc0.z+sh0.z,0.f)*nn, fmaxf(bfhi(v.y)*sc0.w+sh0.w,0.f)*nn);
    w.z = pk2(fmaxf(bflo(v.z)*sc1.x+sh1.x,0.f)*nn, fmaxf(bfhi(v.z)*sc1.y+sh1.y,0.f)*nn);
    w.w = pk2(fmaxf(bflo(v.w)*sc1.z+sh1.z,0.f)*nn, fmaxf(bfhi(v.w)*sc1.w+sh1.w,0.f)*nn);
    *(uint4*)(H2 + (size_t)i*8) = w;
  }
}

// W (K x N fp32) -> Wt (N x K bf16)
__global__ void k_wprep(const float* __restrict__ W, unsigned short* __restrict__ Wt, int K, int N){
  int i = blockIdx.x*blockDim.x + threadIdx.x;
  if(i < K*N){
    int k = i / N, n = i - k*N;
    Wt[(size_t)n*K + k] = f2bf(W[i]);
  }
}

// W3 (256 x 40 fp32) -> Wt3 (64 x 256 bf16), rows >= 40 zero
__global__ void k_wprep3(const float* __restrict__ W3, unsigned short* __restrict__ Wt){
  int i = blockIdx.x*blockDim.x + threadIdx.x;
  if(i < 64*256){
    int n = i >> 8, k = i & 255;
    Wt[i] = (n < 40) ? f2bf(W3[(size_t)k*40 + n]) : (unsigned short)0;
  }
}

// ---------------- BN finalize ----------------

__global__ void k_bnfin(const float* __restrict__ sums, const float* __restrict__ gamma,
                        const float* __restrict__ beta, float* __restrict__ scsh, int M){
  int c = threadIdx.x;
  float mean = sums[c]/(float)M;
  float var  = sums[256+c]/(float)M - mean*mean;
  float sc = gamma[c]*rsqrtf(var + BN_EPS);
  scsh[c] = sc;
  scsh[256+c] = beta[c] - mean*sc;
}

// ---------------- aggregation (wave per (node,col-half), padded CSR) ----------------
// XCD-parity column split: grid 2N, half = bid&1, node = bid>>1. With round-robin
// workgroup->XCD dispatch (bid%8), each XCD touches only one column-half of H ->
// per-L2 working set halves -> higher hit rate on the L2-miss-path-bound gather.

// 128-col rows: half = 64 cols (128B). 8 edge-groups x 8 lanes x uint4. 8 edges/iter.
__global__ __launch_bounds__(64) void k_agg128h(const unsigned short* __restrict__ H,
    const int* __restrict__ rp, const int* __restrict__ esrc,
    const float* __restrict__ norm, unsigned short* __restrict__ out){
  int bid = blockIdx.x;
  int half = bid & 1, node = bid >> 1;
  int lane = threadIdx.x;
  int s0 = rp[node], s1 = rp[node+1];
  int g = lane >> 3, c = lane & 7;
  const unsigned short* Hh = H + half*64;
  float a[8] = {};
  for(int e=s0; e<s1; e+=8){
    int4 A4 = *(const int4*)(esrc+e);
    int4 B4 = *(const int4*)(esrc+e+4);
    int idx = g<4 ? (g==0?A4.x: g==1?A4.y: g==2?A4.z: A4.w)
                  : (g==4?B4.x: g==5?B4.y: g==6?B4.z: B4.w);
    uint4 v = *(const uint4*)(Hh + (size_t)idx*128 + c*8);
    a[0]+=bflo(v.x); a[1]+=bfhi(v.x); a[2]+=bflo(v.y); a[3]+=bfhi(v.y);
    a[4]+=bflo(v.z); a[5]+=bfhi(v.z); a[6]+=bflo(v.w); a[7]+=bfhi(v.w);
  }
  #pragma unroll
  for(int off=8; off<64; off<<=1){
    #pragma unroll
    for(int j=0;j<8;j++) a[j] += __shfl_xor(a[j], off, 64);
  }
  if(g==0){
    float nn = norm[node];
    uint4 w;
    w.x = pk2(a[0]*nn, a[1]*nn);
    w.y = pk2(a[2]*nn, a[3]*nn);
    w.z = pk2(a[4]*nn, a[5]*nn);
    w.w = pk2(a[6]*nn, a[7]*nn);
    *(uint4*)(out + (size_t)node*128 + half*64 + c*8) = w;
  }
}

// 256-col rows: half = 128 cols (256B). 4 edge-groups x 16 lanes x uint4. 8 edges/iter.
__global__ __launch_bounds__(64) void k_agg256h(const unsigned short* __restrict__ H,
    const int* __restrict__ rp, const int* __restrict__ esrc,
    const float* __restrict__ norm, unsigned short* __restrict__ out){
  int bid = blockIdx.x;
  int half = bid & 1, node = bid >> 1;
  int lane = threadIdx.x;
  int s0 = rp[node], s1 = rp[node+1];
  int g = lane >> 4, c = lane & 15;
  const unsigned short* Hh = H + half*128;
  float a[8] = {};
  for(int e=s0; e<s1; e+=8){
    int4 A4 = *(const int4*)(esrc+e);
    int4 B4 = *(const int4*)(esrc+e+4);
    int i0 = g==0?A4.x: g==1?A4.y: g==2?A4.z: A4.w;
    int i1 = g==0?B4.x: g==1?B4.y: g==2?B4.z: B4.w;
    uint4 v0 = *(const uint4*)(Hh + (size_t)i0*256 + c*8);
    uint4 v1 = *(const uint4*)(Hh + (size_t)i1*256 + c*8);
    a[0]+=bflo(v0.x)+bflo(v1.x); a[1]+=bfhi(v0.x)+bfhi(v1.x);
    a[2]+=bflo(v0.y)+bflo(v1.y); a[3]+=bfhi(v0.y)+bfhi(v1.y);
    a[4]+=bflo(v0.z)+bflo(v1.z); a[5]+=bfhi(v0.z)+bfhi(v1.z);
    a[6]+=bflo(v0.w)+bflo(v1.w); a[7]+=bfhi(v0.w)+bfhi(v1.w);
  }
  #pragma unroll
  for(int j=0;j<8;j++){
    a[j] += __shfl_xor(a[j], 16, 64);
    a[j] += __shfl_xor(a[j], 32, 64);
  }
  if(g==0){
    float nn = norm[node];
    uint4 w;
    w.x = pk2(a[0]*nn, a[1]*nn);
    w.y = pk2(a[2]*nn, a[3]*nn);
    w.z = pk2(a[4]*nn, a[5]*nn);
    w.w = pk2(a[6]*nn, a[7]*nn);
    *(uint4*)(out + (size_t)node*256 + half*128 + c*8) = w;
  }
}

// final aggregation: X3p rows 40 bf16 (80B, 16B-aligned since 80=5*16).
__global__ __launch_bounds__(64) void k_agg64(const unsigned short* __restrict__ X3p,
    const int* __restrict__ rp, const int* __restrict__ esrc,
    const float* __restrict__ norm, const float* __restrict__ b3,
    float* __restrict__ out){
  int node = blockIdx.x, lane = threadIdx.x;
  int s0 = rp[node], s1 = rp[node+1];
  int es = lane >> 3, s = lane & 7;
  float a[8] = {};
  for(int e=s0; e<s1; e+=8){
    int4 A4 = *(const int4*)(esrc+e);
    int4 B4 = *(const int4*)(esrc+e+4);
    int idx = es==0?A4.x: es==1?A4.y: es==2?A4.z: es==3?A4.w:
              es==4?B4.x: es==5?B4.y: es==6?B4.z: B4.w;
    if(s<5){
      uint4 v = *(const uint4*)(X3p + (size_t)idx*40 + s*8);
      a[0]+=bflo(v.x); a[1]+=bfhi(v.x); a[2]+=bflo(v.y); a[3]+=bfhi(v.y);
      a[4]+=bflo(v.z); a[5]+=bfhi(v.z); a[6]+=bflo(v.w); a[7]+=bfhi(v.w);
    }
  }
  #pragma unroll
  for(int off=8; off<64; off<<=1){
    #pragma unroll
    for(int j=0;j<8;j++) a[j] += __shfl_xor(a[j], off, 64);
  }
  bool act = s < 5;   // cols s*8..s*8+7 < 40
  float nn = norm[node];
  float bv[8] = {};
  if(act){
    float4 t0 = *(const float4*)(b3 + s*8);
    float4 t1 = *(const float4*)(b3 + s*8 + 4);
    bv[0]=t0.x; bv[1]=t0.y; bv[2]=t0.z; bv[3]=t0.w;
    bv[4]=t1.x; bv[5]=t1.y; bv[6]=t1.z; bv[7]=t1.w;
  }
  float v[8];
  float mx = -INFINITY;
  #pragma unroll
  for(int j=0;j<8;j++){
    v[j] = act ? (a[j]*nn + bv[j]) : -INFINITY;
    mx = fmaxf(mx, v[j]);
  }
  #pragma unroll
  for(int off=32; off; off>>=1) mx = fmaxf(mx, __shfl_xor(mx, off, 64));
  float sum = 0.f;
  if(act && es==0){
    #pragma unroll
    for(int j=0;j<8;j++) sum += expf(v[j]-mx);
  }
  #pragma unroll
  for(int off=32; off; off>>=1) sum += __shfl_xor(sum, off, 64);
  float lse = logf(sum);
  if(act && es==0){
    float4 o0, o1;
    o0.x=v[0]-mx-lse; o0.y=v[1]-mx-lse; o0.z=v[2]-mx-lse; o0.w=v[3]-mx-lse;
    o1.x=v[4]-mx-lse; o1.y=v[5]-mx-lse; o1.z=v[6]-mx-lse; o1.w=v[7]-mx-lse;
    *(float4*)(out + (size_t)node*40 + s*8) = o0;
    *(float4*)(out + (size_t)node*40 + s*8 + 4) = o1;
  }
}

// ---------------- MFMA GEMM: C = A*Bt^T + bias (bf16 out) + fused column stats ----------------

__global__ __launch_bounds__(256) void k_mgemm(
    const unsigned short* __restrict__ A, const unsigned short* __restrict__ Bt,
    const float* __restrict__ bias, unsigned short* __restrict__ C,
    float* __restrict__ sums, int M, int K, int Nn){
  __shared__ unsigned short As[128*64];
  __shared__ unsigned short Bs[128*64];
  int nt = Nn >> 7;
  int bm = blockIdx.x / nt, bn = blockIdx.x % nt;
  int m0 = bm*128, n0 = bn*128;
  int tid = threadIdx.x;
  int wave = tid >> 6, lane = tid & 63;
  int wm = (wave>>1)*64, wn = (wave&1)*64;
  int lrow = lane & 15, lq = lane >> 4;
  int srow = lane >> 3;
  int sx = ((lane & 7) ^ srow) * 8;
  f32x4 acc[4][4] = {};
  for(int k0=0; k0<K; k0+=64){
    __syncthreads();
    #pragma unroll
    for(int c4=0;c4<4;c4++){
      int c = wave*4 + c4;
      int grow = c*8 + srow;
      const unsigned short* ga = A + (size_t)(m0+grow)*K + k0 + sx;
      __builtin_amdgcn_global_load_lds((const __attribute__((address_space(1))) void*)ga,
          (__attribute__((address_space(3))) void*)(As + (size_t)c*512), 16, 0, 0);
      const unsigned short* gb = Bt + (size_t)(n0+grow)*K + k0 + sx;
      __builtin_amdgcn_global_load_lds((const __attribute__((address_space(1))) void*)gb,
          (__attribute__((address_space(3))) void*)(Bs + (size_t)c*512), 16, 0, 0);
    }
    __syncthreads();
    #pragma unroll
    for(int kk=0;kk<2;kk++){
      short8 af[4], bf[4];
      #pragma unroll
      for(int i=0;i<4;i++){
        int Ra = wm + i*16 + lrow;
        int ca = (kk*4 + lq) ^ (Ra & 7);
        af[i] = *(const short8*)(As + Ra*64 + ca*8);
        int Rb = wn + i*16 + lrow;
        int cb = (kk*4 + lq) ^ (Rb & 7);
        bf[i] = *(const short8*)(Bs + Rb*64 + cb*8);
      }
      #pragma unroll
      for(int i=0;i<4;i++)
        #pragma unroll
        for(int j=0;j<4;j++)
          acc[i][j] = __builtin_amdgcn_mfma_f32_16x16x32_bf16(af[i], bf[j], acc[i][j], 0, 0, 0);
    }
  }
  // epilogue: write C (bf16) and accumulate column sum/sumsq for BN stats
  #pragma unroll
  for(int j=0;j<4;j++){
    int col = n0 + wn + j*16 + lrow;
    float bj = bias[col];
    float s=0.f, s2=0.f;
    #pragma unroll
    for(int i=0;i<4;i++){
      #pragma unroll
      for(int r=0;r<4;r++){
        int row = m0 + wm + i*16 + lq*4 + r;
        if(row < M){
          float v = acc[i][j][r] + bj;
          s += v; s2 += v*v;
          C[(size_t)row*Nn + col] = f2bf(v);
        }
      }
    }
    s  += __shfl_xor(s, 16, 64);  s  += __shfl_xor(s, 32, 64);
    s2 += __shfl_xor(s2, 16, 64); s2 += __shfl_xor(s2, 32, 64);
    if(lq == 0){
      atomicAdd(&sums[col], s);
      atomicAdd(&sums[256+col], s2);
    }
  }
}

// layer-3: 128x64 tile; A-staging applies BN+ReLU (scsh) on the fly (reg->LDS);
// out X3p bf16 stride 40 (*rownorm), cols>=40 discarded. Bt = Wt3 (64 x K).
__global__ __launch_bounds__(256) void k_mgemm3(
    const unsigned short* __restrict__ Zin, const unsigned short* __restrict__ Bt,
    const float* __restrict__ scsh, const float* __restrict__ rownorm,
    unsigned short* __restrict__ X3p, int M, int K){
  __shared__ unsigned short As[128*64];
  __shared__ unsigned short Bs[64*64];
  int m0 = blockIdx.x*128;
  int tid = threadIdx.x;
  int wave = tid >> 6, lane = tid & 63;
  int wm = wave*32;
  int lrow = lane & 15, lq = lane >> 4;
  int srow = lane >> 3;
  int sx = ((lane & 7) ^ srow) * 8;
  f32x4 acc[2][4] = {};
  for(int k0=0; k0<K; k0+=64){
    // prefetch raw A (pre-BN Z2) to regs while previous iter computes
    uint4 raw[4];
    #pragma unroll
    for(int c4=0;c4<4;c4++){
      int c = wave*4 + c4;
      int grow = c*8 + srow;
      raw[c4] = *(const uint4*)(Zin + (size_t)(m0+grow)*K + k0 + sx);
    }
    float4 sc0 = *(const float4*)(scsh + k0 + sx);
    float4 sc1 = *(const float4*)(scsh + k0 + sx + 4);
    float4 sh0 = *(const float4*)(scsh + 256 + k0 + sx);
    float4 sh1 = *(const float4*)(scsh + 256 + k0 + sx + 4);
    __syncthreads();                 // previous iter's LDS reads done
    #pragma unroll
    for(int c4=0;c4<4;c4++){
      int c = wave*4 + c4;
      uint4 w;
      w.x = pk2(fmaxf(bflo(raw[c4].x)*sc0.x+sh0.x,0.f), fmaxf(bfhi(raw[c4].x)*sc0.y+sh0.y,0.f));
      w.y = pk2(fmaxf(bflo(raw[c4].y)*sc0.z+sh0.z,0.f), fmaxf(bfhi(raw[c4].y)*sc0.w+sh0.w,0.f));
      w.z = pk2(fmaxf(bflo(raw[c4].z)*sc1.x+sh1.x,0.f), fmaxf(bfhi(raw[c4].z)*sc1.y+sh1.y,0.f));
      w.w = pk2(fmaxf(bflo(raw[c4].w)*sc1.z+sh1.z,0.f), fmaxf(bfhi(raw[c4].w)*sc1.w+sh1.w,0.f));
      *(uint4*)(As + (size_t)c*512 + (size_t)lane*8) = w;
    }
    #pragma unroll
    for(int c4=0;c4<2;c4++){
      int c = wave*2 + c4;
      int grow = c*8 + srow;            // 0..63
      const unsigned short* gb = Bt + (size_t)grow*K + k0 + sx;
      __builtin_amdgcn_global_load_lds((const __attribute__((address_space(1))) void*)gb,
          (__attribute__((address_space(3))) void*)(Bs + (size_t)c*512), 16, 0, 0);
    }
    __syncthreads();
    #pragma unroll
    for(int kk=0;kk<2;kk++){
      short8 af[2], bf[4];
      #pragma unroll
      for(int i=0;i<2;i++){
        int Ra = wm + i*16 + lrow;
        int ca = (kk*4 + lq) ^ (Ra & 7);
        af[i] = *(const short8*)(As + Ra*64 + ca*8);
      }
      #pragma unroll
      for(int j=0;j<4;j++){
        int Rb = j*16 + lrow;
        int cb = (kk*4 + lq) ^ (Rb & 7);
        bf[j] = *(const short8*)(Bs + Rb*64 + cb*8);
      }
      #pragma unroll
      for(int i=0;i<2;i++)
        #pragma unroll
        for(int j=0;j<4;j++)
          acc[i][j] = __builtin_amdgcn_mfma_f32_16x16x32_bf16(af[i], bf[j], acc[i][j], 0, 0, 0);
    }
  }
  #pragma unroll
  for(int j=0;j<4;j++){
    int col = j*16 + lrow;
    if(col < 40){
      #pragma unroll
      for(int i=0;i<2;i++){
        #pragma unroll
        for(int r=0;r<4;r++){
          int row = m0 + wm + i*16 + lq*4 + r;
          if(row < M) X3p[(size_t)row*40 + col] = f2bf(acc[i][j][r] * rownorm[row]);
        }
      }
    }
  }
}

// ---------------- launch ----------------

extern "C" void kernel_launch(void* const* d_in, const int* in_sizes, int n_in,
                              void* d_out, int out_size, void* d_ws, size_t ws_size,
                              hipStream_t stream){
  const float* x   = (const float*)d_in[0];
  const int*   src = (const int*)d_in[1];
  const int*   dst = (const int*)d_in[2];
  const float* W1  = (const float*)d_in[3];
  const float* b1  = (const float*)d_in[4];
  const float* g1  = (const float*)d_in[5];
  const float* be1 = (const float*)d_in[6];
  const float* W2  = (const float*)d_in[7];
  const float* b2  = (const float*)d_in[8];
  const float* g2  = (const float*)d_in[9];
  const float* be2 = (const float*)d_in[10];
  const float* W3  = (const float*)d_in[11];
  const float* b3  = (const float*)d_in[12];
  float* out = (float*)d_out;
  const int N = NN;
  const int E = in_sizes[1];

  char* p = (char*)d_ws;
  size_t off = 0;
  auto alloc = [&](size_t bytes)->void*{
    void* r = p + off;
    off += (bytes + 511) & ~(size_t)511;
    return r;
  };
  // Footprint ~168 MB — under the ~229 MB known-good high-water mark.
  int*   bcnt  = (int*)  alloc((size_t)NBUCK*16*4);  // line-padded bucket counters
  float* sums1 = (float*)alloc(2048);
  float* sums2 = (float*)alloc(2048);
  size_t zero_bytes = off;                           // bcnt|sums zeroed each call
  int*   rp    = (int*)  alloc((size_t)(N+1)*4);
  float* norm  = (float*)alloc((size_t)(N+1)*4);
  float* scsh1 = (float*)alloc(2048);
  float* scsh2 = (float*)alloc(2048);
  int*   ptot  = (int*)  alloc((size_t)NBUCK*4);
  int*   bbase = (int*)  alloc((size_t)(NBUCK+1)*4);
  unsigned short* Wt1 = (unsigned short*)alloc((size_t)256*128*2);
  unsigned short* Wt2 = (unsigned short*)alloc((size_t)256*256*2);
  unsigned short* Wt3 = (unsigned short*)alloc((size_t)64*256*2);
  int*   esrc  = (int*)  alloc((size_t)(E + 7*N + 16)*4);            // pad-8 CSR
  unsigned short* Hx  = (unsigned short*)alloc((size_t)(N+1)*128*2); // x*norm + zero row
  unsigned short* M1  = (unsigned short*)alloc((size_t)N*128*2);     // agg128 out
  unsigned short* Mb2 = (unsigned short*)alloc((size_t)N*256*2);     // agg256 out
  unsigned short* Z   = (unsigned short*)alloc((size_t)(N+1)*256*2); // mgemm out + zero row
  unsigned short* X3p = (unsigned short*)alloc((size_t)(N+1)*40*2);  // layer-3 proj (40-col)
  // epairs (packed bucket words, 782*6400*4 = 20MB) aliases Mb2 (51.2MB):
  // dead before k_agg256h writes Mb2 on this single stream.
  int* epairs = (int*)Mb2;
  // H2 = relu(bn(Z1))*norm, (N+1)x256 bf16 = 51,200,512 B. Aliases Hx(25,600,512)
  // + M1(25,600,000) — both dead after layer-1 mgemm; ends exactly at Mb2.
  unsigned short* H2 = Hx;
  (void)ws_size; (void)n_in; (void)out_size;

  hipMemsetAsync(d_ws, 0, zero_bytes, stream);

  k_b1    <<<(E+T1_TILE-1)/T1_TILE,256,0,stream>>>(src, dst, bcnt, epairs, E);
  k_b2a   <<<NBUCK,256,0,stream>>>(epairs, bcnt, norm, ptot);
  k_scanB <<<1,1024,0,stream>>>(ptot, bbase, rp, norm);
  k_b2b   <<<NBUCK,256,0,stream>>>(epairs, bcnt, bbase, rp, esrc);
  k_zeropad<<<1,256,0,stream>>>(Hx, X3p, Z);
  k_wprep  <<<(128*256+255)/256,256,0,stream>>>(W1, Wt1, 128, 256);
  k_wprep  <<<(256*256+255)/256,256,0,stream>>>(W2, Wt2, 256, 256);
  k_wprep3 <<<(64*256+255)/256,256,0,stream>>>(W3, Wt3);

  // layer 1: Hx = x*norm -> agg128h (XCD col-split) -> MFMA @W1+b1 (+stats) -> Z1(bf16)
  k_scale_x4<<<(N*32+255)/256,256,0,stream>>>(x, norm, Hx, N*32);
  k_agg128h<<<2*N,64,0,stream>>>(Hx, rp, esrc, norm, M1);
  k_mgemm  <<<((N+127)/128)*2,256,0,stream>>>(M1, Wt1, b1, Z, sums1, N, 128, 256);
  k_bnfin  <<<1,256,0,stream>>>(sums1, g1, be1, scsh1, N);

  // layer 2: H2 = relu(bn(Z1))*norm (one pass) -> agg256h (XCD col-split) -> MFMA -> Z2
  k_bnrelu <<<((N+1)*32+255)/256,256,0,stream>>>(Z, scsh1, norm, H2, (N+1)*32);
  k_agg256h<<<2*N,64,0,stream>>>(H2, rp, esrc, norm, Mb2);
  k_mgemm  <<<((N+127)/128)*2,256,0,stream>>>(Mb2, Wt2, b2, Z, sums2, N, 256, 256);
  k_bnfin  <<<1,256,0,stream>>>(sums2, g2, be2, scsh2, N);

  // layer 3: mgemm3 applies BN+ReLU to Z2 in staging, X3p = (relu(bn(Z2))@W3p)*norm
  k_mgemm3 <<<(N+127)/128,256,0,stream>>>(Z, Wt3, scsh2, norm, X3p, N, 256);
  k_agg64  <<<N,64,0,stream>>>(X3p, rp, esrc, norm, b3, out);
}